// Round 19
// baseline (187.626 us; speedup 1.0000x reference)
//
#include <hip/hip_runtime.h>

typedef unsigned short u16;
typedef unsigned int u32;
typedef __attribute__((ext_vector_type(8))) short bf16x8;
typedef __attribute__((ext_vector_type(4))) float f32x4;

#define CH 40
#define IW 258                   // ring-padded width (256 + 2)
#define IWCH (IW * CH)           // 10320
#define IMG_CL (IW * IW * CH)    // u16 elements per image, channel-last padded
#define WT_SET (48 * 384)        // u16: w3 row-major set (wgtmul)
#define WCM_SET (48 * 40 * 8)    // u16: after_w chunk-major set (conv7) = 15360
#define WSC_SET (46 * 40 * 8)    // u16 compressed set: 45 real + 1 zero = 14720

// NOTE (r18 lesson): global_load_lds dest is wave-uniform-base + lane*16;
// only use it in trailing-predicated single-branch form (first active lane 0).
#define GLDS16(g, l) __builtin_amdgcn_global_load_lds( \
    (const __attribute__((address_space(1))) void*)(g), \
    (__attribute__((address_space(3))) void*)(l), 16, 0, 0)

__device__ __forceinline__ float b2f(u16 u) {
  union { u32 i; float f; } v; v.i = ((u32)u) << 16; return v.f;
}
// HW packed f32->bf16 (RNE)
__device__ __forceinline__ u32 pkbf(float lo, float hi) {
  u32 r;
  asm("v_cvt_pk_bf16_f32 %0, %1, %2" : "=v"(r) : "v"(lo), "v"(hi));
  return r;
}
__device__ __forceinline__ u16 f2b(float f) {
  union { float f; u32 i; } v; v.f = f;
  u32 r = v.i + 0x7fffu + ((v.i >> 16) & 1u);
  return (u16)(r >> 16);
}
__device__ __forceinline__ u32 addbf2(u32 a, u32 b) {
  union { u32 i; float f; } lo_a, lo_b, hi_a, hi_b;
  lo_a.i = a << 16; lo_b.i = b << 16;
  hi_a.i = a & 0xffff0000u; hi_b.i = b & 0xffff0000u;
  return pkbf(lo_a.f + lo_b.f, hi_a.f + hi_b.f);
}
// tanh-approx gelu (validated r10)
__device__ __forceinline__ float actf(float t, int ACT) {
  if (ACT == 1) {
    float u2 = t * (1.5957691216057308f + 0.07135481627000862f * t * t);
    float e = __expf(u2);
    return t - t / (e + 1.f);
  }
  if (ACT == 2) return fmaxf(t, 0.f);
  return t;
}

// ---- weights: w3 rm + after cm + compressed 46-chunk x3 ------------------
__global__ __launch_bounds__(256)
void prep_w_k(const float* __restrict__ w0, const float* __restrict__ w1,
              const float* __restrict__ w2, const float* __restrict__ w3,
              const float* __restrict__ w4, u16* __restrict__ wt4,
              u16* __restrict__ wcma, u16* __restrict__ wsc)
{
  int i = blockIdx.x * 256 + threadIdx.x;
  if (i >= WT_SET + WCM_SET + 3 * WSC_SET) return;
  if (i < WT_SET) {
    int k = i % 384;
    int oc = i / 384;
    u16 v = 0;
    if (oc < 40 && k < 40) v = f2b(w4[oc * 40 + k]);
    wt4[i] = v;
  } else if (i < WT_SET + WCM_SET) {
    int j = i - WT_SET;
    int c = j / 320;
    int rem = j - c * 320;
    int oc = rem >> 3;
    int e = rem & 7;
    int k = c * 8 + e;
    int dy = k >> 7;
    int r = k & 127;
    u16 v = 0;
    if (r < 120) {
      int dx = r / 40;
      int ic = r - dx * 40;
      v = f2b(w3[((oc * 40 + ic) * 3 + dy) * 3 + dx]);
    }
    wcma[j] = v;
  } else {
    int j2 = i - WT_SET - WCM_SET;
    int set3 = j2 / WSC_SET;
    int r3 = j2 - set3 * WSC_SET;
    int c2 = r3 / 320;
    int rem = r3 - c2 * 320;
    int oc = rem >> 3;
    int e = rem & 7;
    u16 v = 0;
    if (c2 < 45) {
      int dy = c2 / 15, cc = c2 % 15;
      int dx = cc / 5, icq = cc % 5;
      int ic = icq * 8 + e;
      const float* w = (set3 == 0) ? w0 : (set3 == 1) ? w2 : w1;
      v = f2b(w[((oc * 40 + ic) * 3 + dy) * 3 + dx]);
    }
    wsc[j2] = v;
  }
}

// ---- zero the halo rings of cl_a -----------------------------------------
__global__ __launch_bounds__(256)
void ringz_k(u16* __restrict__ cla)
{
  const int n = blockIdx.x / IW;
  const int yr = blockIdx.x % IW;
  const int t = threadIdx.x;
  const size_t base = (size_t)n * IMG_CL + (size_t)yr * IWCH;
  const uint4 z = {0u, 0u, 0u, 0u};
  if (yr == 0 || yr == IW - 1) {
    for (int i = t; i < IWCH / 8; i += 256) ((uint4*)(cla + base))[i] = z;
    return;
  }
  if (t < 5) {
    ((uint4*)(cla + base))[t] = z;
  } else if (t < 10) {
    ((uint4*)(cla + base + (size_t)(IW - 1) * CH))[t - 5] = z;
  }
}

// K-step body for fconv2p (PHASE 0: slots dy*15+c / 30-zero; 1: c / 15-zero)
#define KSTEP_F(s, PHASE, ACC)                                               \
  {                                                                          \
    const int dy = (s) >> 2;                                                 \
    const int c = (((s) & 3) << 2) + g;                                      \
    int dx, icb;                                                             \
    if (c >= 15)      { dx = 0; icb = 0; }                                   \
    else if (c >= 10) { dx = 2; icb = (c - 10) * 8; }                        \
    else if (c >= 5)  { dx = 1; icb = (c - 5) * 8; }                         \
    else              { dx = 0; icb = c * 8; }                               \
    const int abase = (ry + dy) * (66 * CH) + ((h * 2) * 16 + m + dx) * CH + icb; \
    bf16x8 a0 = *(const bf16x8*)(s_in + abase);                              \
    bf16x8 a1 = *(const bf16x8*)(s_in + abase + 16 * CH);                    \
    const int slot = (PHASE == 0) ? ((c == 15) ? 30 : (dy * 15 + c))         \
                                  : ((c == 15) ? 15 : c);                    \
    const u16* wrow = s_w + slot * 320;                                      \
    bf16x8 b0 = *(const bf16x8*)(wrow + m * 8);                              \
    bf16x8 b1 = *(const bf16x8*)(wrow + (m + 16) * 8);                       \
    bf16x8 b2 = *(const bf16x8*)(wrow + (m >= 8 ? 312 : (m + 32) * 8));      \
    ACC[0][0] = __builtin_amdgcn_mfma_f32_16x16x32_bf16(b0, a0, ACC[0][0], 0, 0, 0); \
    ACC[1][0] = __builtin_amdgcn_mfma_f32_16x16x32_bf16(b0, a1, ACC[1][0], 0, 0, 0); \
    ACC[0][1] = __builtin_amdgcn_mfma_f32_16x16x32_bf16(b1, a0, ACC[0][1], 0, 0, 0); \
    ACC[1][1] = __builtin_amdgcn_mfma_f32_16x16x32_bf16(b1, a1, ACC[1][1], 0, 0, 0); \
    ACC[0][2] = __builtin_amdgcn_mfma_f32_16x16x32_bf16(b2, a0, ACC[0][2], 0, 0, 0); \
    ACC[1][2] = __builtin_amdgcn_mfma_f32_16x16x32_bf16(b2, a1, ACC[1][2], 0, 0, 0); \
  }

// ---- fused conv1+conv5, 512 thr / 8 waves, split weight staging ----------
// LDS: x 31,680 B + weight buffer 19,840 B = 51,520 B -> 3 blocks/CU
__global__ __launch_bounds__(512, 6)
void fconv2p_k(const float* __restrict__ xg, const u16* __restrict__ wscA,
               const u16* __restrict__ wscB, const float* __restrict__ biasA,
               const float* __restrict__ biasB, u16* __restrict__ outA,
               u16* __restrict__ outB)
{
  __shared__ __align__(16) u16 s_mem[15840 + 9920];  // 51,520 B
  u16* s_in = s_mem;
  u16* s_w  = s_mem + 15840;                         // 31 chunk slots

  const int tid = threadIdx.x;
  const int bid = ((int)blockIdx.x & 7) * 256 + ((int)blockIdx.x >> 3);
  const int n = bid >> 8;
  const int tb = bid & 255;
  const int y0 = (tb >> 2) << 2;
  const int x0 = (tb & 3) << 6;

  const uint4 z4 = {0u, 0u, 0u, 0u};

  // phase-0 weight stage: chunks 0..29 linear (trailing-predicated GLDS16);
  // slot 30 = zero chunk via plain ds_write (r18 FIX: no divergent GLDS16)
  #pragma unroll
  for (int k = 0; k < 3; ++k) {
    int i = tid + (k << 9);
    if (i < 1200) GLDS16(wscA + i * 8, s_w + i * 8);
  }
  if (tid < 40) ((uint4*)(s_w + 9600))[tid] = z4;
  // stage x tile (6 rows x 66 px x 40 ic), packed-converting
  const float* xsrc = xg + (size_t)n * CH * 65536;
  if (tid < 396) {
    int slot = tid;
    int r = slot / 66, p = slot - r * 66;
    int gy = y0 + r - 1, gx = x0 + p - 1;
    __attribute__((aligned(16))) u32 buf[20];
    if ((unsigned)gy < 256u && (unsigned)gx < 256u) {
      const float* xp = xsrc + (size_t)gy * 256 + gx;
      #pragma unroll
      for (int icp = 0; icp < 20; ++icp)
        buf[icp] = pkbf(xp[(size_t)(2 * icp) * 65536],
                        xp[(size_t)(2 * icp + 1) * 65536]);
    } else {
      #pragma unroll
      for (int icp = 0; icp < 20; ++icp) buf[icp] = 0u;
    }
    u16* dst = s_in + slot * 40;
    #pragma unroll
    for (int q = 0; q < 5; ++q) ((uint4*)dst)[q] = ((const uint4*)buf)[q];
  }
  __syncthreads();

  const int w = tid >> 6;
  const int ry = w >> 1;                       // output row y0+ry
  const int h = w & 1;                         // x half
  const int l = tid & 63;
  const int g = l >> 4;
  const int m = l & 15;

  f32x4 accA[2][3], accB[2][3];
  #pragma unroll
  for (int xt = 0; xt < 2; ++xt)
    #pragma unroll
    for (int tt = 0; tt < 3; ++tt) {
      accA[xt][tt] = (f32x4){0.f, 0.f, 0.f, 0.f};
      accB[xt][tt] = (f32x4){0.f, 0.f, 0.f, 0.f};
    }

  // ---- pass A, dy 0..1 ---------------------------------------------------
  #pragma unroll
  for (int s = 0; s < 8; ++s) KSTEP_F(s, 0, accA)
  __syncthreads();
  // phase-1 stage: chunks 30..45 linear -> slots 0..15 (incl. stored zero 45)
  #pragma unroll
  for (int k = 0; k < 2; ++k) {
    int i = tid + (k << 9);
    if (i < 640) GLDS16(wscA + 9600 + i * 8, s_w + i * 8);
  }
  __syncthreads();
  // ---- pass A, dy 2 ------------------------------------------------------
  #pragma unroll
  for (int s = 8; s < 12; ++s) KSTEP_F(s, 1, accA)
  __syncthreads();

  // ---- pass B phase 0 ----------------------------------------------------
  #pragma unroll
  for (int k = 0; k < 3; ++k) {
    int i = tid + (k << 9);
    if (i < 1200) GLDS16(wscB + i * 8, s_w + i * 8);
  }
  if (tid < 40) ((uint4*)(s_w + 9600))[tid] = z4;   // r18 FIX
  __syncthreads();
  #pragma unroll
  for (int s = 0; s < 8; ++s) KSTEP_F(s, 0, accB)
  __syncthreads();
  #pragma unroll
  for (int k = 0; k < 2; ++k) {
    int i = tid + (k << 9);
    if (i < 640) GLDS16(wscB + 9600 + i * 8, s_w + i * 8);
  }
  __syncthreads();
  #pragma unroll
  for (int s = 8; s < 12; ++s) KSTEP_F(s, 1, accB)
  __syncthreads();                             // all reads of s_w/s_in done

  float4 bvA[3], bvB[3];
  bvA[0] = *(const float4*)(biasA + 4 * g);
  bvA[1] = *(const float4*)(biasA + 16 + 4 * g);
  bvA[2] = (g < 2) ? *(const float4*)(biasA + 32 + 4 * g) : make_float4(0.f, 0.f, 0.f, 0.f);
  bvB[0] = *(const float4*)(biasB + 4 * g);
  bvB[1] = *(const float4*)(biasB + 16 + 4 * g);
  bvB[2] = (g < 2) ? *(const float4*)(biasB + 32 + 4 * g) : make_float4(0.f, 0.f, 0.f, 0.f);

  // restage regions live in the now-dead x tile (4 x 5120 B <= 31,680 B)
  char* so = (char*)s_in + ry * 5120;
  const int rdrow = tid >> 7;
  const int l2 = tid & 127;
  const size_t rowu_rd = (size_t)n * IMG_CL
                       + ((size_t)(y0 + rdrow + 1) * IW + (x0 + 1)) * CH;

  // ---- pass A epilogue ---------------------------------------------------
  #pragma unroll
  for (int tt = 0; tt < 3; ++tt) {
    if (tt == 2 && g >= 2) continue;
    #pragma unroll
    for (int xt = 0; xt < 2; ++xt) {
      const int pxl = (2 * h + xt) * 16 + m;
      float v[4];
      #pragma unroll
      for (int i = 0; i < 4; ++i)
        v[i] = actf(accA[xt][tt][i] + ((const float*)&bvA[tt])[i], 1);
      uint2 pk;
      pk.x = pkbf(v[0], v[1]);
      pk.y = pkbf(v[2], v[3]);
      int byt = pxl * 80 + (16 * tt + 4 * g) * 2;
      byt ^= ((pxl >> 3) & 7) << 4;
      *(uint2*)(so + byt) = pk;
    }
  }
  __syncthreads();
  {
    const char* ro = (const char*)s_in + rdrow * 5120;
    #pragma unroll
    for (int pass = 0; pass < 3; ++pass) {
      int j = l2 + (pass << 7);
      if (j < 320) {
        int px = j / 5, oct = j % 5;
        int byt = px * 80 + oct * 16;
        byt ^= ((px >> 3) & 7) << 4;
        uint4 d = *(const uint4*)(ro + byt);
        *(uint4*)(outA + rowu_rd + (size_t)px * 40 + oct * 8) = d;
      }
    }
  }
  __syncthreads();

  // ---- pass B epilogue ---------------------------------------------------
  #pragma unroll
  for (int tt = 0; tt < 3; ++tt) {
    if (tt == 2 && g >= 2) continue;
    #pragma unroll
    for (int xt = 0; xt < 2; ++xt) {
      const int pxl = (2 * h + xt) * 16 + m;
      float v[4];
      #pragma unroll
      for (int i = 0; i < 4; ++i)
        v[i] = actf(accB[xt][tt][i] + ((const float*)&bvB[tt])[i], 2);
      uint2 pk;
      pk.x = pkbf(v[0], v[1]);
      pk.y = pkbf(v[2], v[3]);
      int byt = pxl * 80 + (16 * tt + 4 * g) * 2;
      byt ^= ((pxl >> 3) & 7) << 4;
      *(uint2*)(so + byt) = pk;
    }
  }
  __syncthreads();
  {
    const char* ro = (const char*)s_in + rdrow * 5120;
    #pragma unroll
    for (int pass = 0; pass < 3; ++pass) {
      int j = l2 + (pass << 7);
      if (j < 320) {
        int px = j / 5, oct = j % 5;
        int byt = px * 80 + oct * 16;
        byt ^= ((px >> 3) & 7) << 4;
        uint4 d = *(const uint4*)(ro + byt);
        *(uint4*)(outB + rowu_rd + (size_t)px * 40 + oct * 8) = d;
      }
    }
  }
}

// ---- conv7: all-LDS MFMA conv, planar f32 out, split weight staging ------
// LDS: x 31,680 + weight buffer 15,360 = 47,040 B -> 3 blocks/CU
__global__ __launch_bounds__(512, 6)
void convl_k(const u16* __restrict__ incl, const u16* __restrict__ wcm,
             const float* __restrict__ bias, float* __restrict__ outp)
{
  __shared__ __align__(16) u16 s_mem[15840 + 7680];  // 47,040 B
  u16* s_in = s_mem;
  u16* s_w  = s_mem + 15840;                         // 24 chunk slots

  const int tid = threadIdx.x;
  const int bid = ((int)blockIdx.x & 7) * 256 + ((int)blockIdx.x >> 3);
  const int n = bid >> 8;
  const int tb = bid & 255;
  const int y0 = (tb >> 2) << 2;
  const int x0 = (tb & 3) << 6;

  const u16* src = incl + (size_t)n * IMG_CL + ((size_t)y0 * IW + x0) * CH;
  #pragma unroll
  for (int k = 0; k < 4; ++k) {
    int i = tid + (k << 9);
    if (i < 1980) {
      int r = i / 330, o = i - r * 330;
      GLDS16(src + (size_t)r * IWCH + o * 8, s_in + i * 8);
    }
  }
  #pragma unroll
  for (int k = 0; k < 2; ++k) {                // chunks 0..23 -> slots 0..23
    int i = tid + (k << 9);
    if (i < 960) GLDS16(wcm + i * 8, s_w + i * 8);
  }
  __syncthreads();

  const int w = tid >> 6;
  const int ry = w >> 1;
  const int h = w & 1;
  const int l = tid & 63;
  const int g = l >> 4;
  const int m = l & 15;

  f32x4 acc[2][3];
  #pragma unroll
  for (int xt = 0; xt < 2; ++xt)
    #pragma unroll
    for (int tt = 0; tt < 3; ++tt) acc[xt][tt] = (f32x4){0.f, 0.f, 0.f, 0.f};

  #pragma unroll
  for (int s = 0; s < 12; ++s) {
    if (s == 6) {
      __syncthreads();                         // all reads of slots 0..23 done
      #pragma unroll
      for (int k = 0; k < 2; ++k) {            // chunks 24..47 -> slots 0..23
        int i = tid + (k << 9);
        if (i < 960) GLDS16(wcm + 7680 + i * 8, s_w + i * 8);
      }
      __syncthreads();                         // phase-1 weights landed
    }
    const int dy = s >> 2;
    const int c = ((s & 3) << 2) + g;
    int dx, icb;
    if (c >= 15)      { dx = 0; icb = 0; }
    else if (c >= 10) { dx = 2; icb = (c - 10) * 8; }
    else if (c >= 5)  { dx = 1; icb = (c - 5) * 8; }
    else              { dx = 0; icb = c * 8; }
    const int abase = (ry + dy) * (66 * CH) + ((h * 2) * 16 + m + dx) * CH + icb;
    bf16x8 a0 = *(const bf16x8*)(s_in + abase);
    bf16x8 a1 = *(const bf16x8*)(s_in + abase + 16 * CH);

    const int ch = (s << 2) + g;
    const int slot = (s < 6) ? ch : (ch - 24);
    const u16* wrow = s_w + slot * 320;
    bf16x8 b0 = *(const bf16x8*)(wrow + m * 8);
    bf16x8 b1 = *(const bf16x8*)(wrow + (m + 16) * 8);
    bf16x8 b2 = *(const bf16x8*)(wrow + (m >= 8 ? 312 : (m + 32) * 8));

    acc[0][0] = __builtin_amdgcn_mfma_f32_16x16x32_bf16(a0, b0, acc[0][0], 0, 0, 0);
    acc[1][0] = __builtin_amdgcn_mfma_f32_16x16x32_bf16(a1, b0, acc[1][0], 0, 0, 0);
    acc[0][1] = __builtin_amdgcn_mfma_f32_16x16x32_bf16(a0, b1, acc[0][1], 0, 0, 0);
    acc[1][1] = __builtin_amdgcn_mfma_f32_16x16x32_bf16(a1, b1, acc[1][1], 0, 0, 0);
    acc[0][2] = __builtin_amdgcn_mfma_f32_16x16x32_bf16(a0, b2, acc[0][2], 0, 0, 0);
    acc[1][2] = __builtin_amdgcn_mfma_f32_16x16x32_bf16(a1, b2, acc[1][2], 0, 0, 0);
  }

  const int y = y0 + ry;
  const float bv0 = bias[m];
  const float bv1 = bias[m + 16];
  const float bv2 = (m < 8) ? bias[m + 32] : 0.f;
  #pragma unroll
  for (int tt = 0; tt < 3; ++tt) {
    const int oc = m + 16 * tt;
    if (tt == 2 && m >= 8) continue;
    const float bv = (tt == 0) ? bv0 : (tt == 1) ? bv1 : bv2;
    #pragma unroll
    for (int xt = 0; xt < 2; ++xt) {
      const int xb = x0 + (2 * h + xt) * 16 + 4 * g;
      float v[4];
      #pragma unroll
      for (int i = 0; i < 4; ++i) v[i] = acc[xt][tt][i] + bv;
      *(float4*)(outp + (((size_t)(n * CH + oc)) << 16) + ((size_t)y << 8) + xb)
          = make_float4(v[0], v[1], v[2], v[3]);
    }
  }
}

// ---- SPARSE conv2 (r13-verified) -----------------------------------------
__global__ __launch_bounds__(256, 2)
void sconv_k(const u16* __restrict__ cla, const u16* __restrict__ wsc,
             const float* __restrict__ bias, u16* __restrict__ ddc)
{
  __shared__ __align__(16) u16 s_mem[32640];   // s_in 17920 + s_w 14720
  u16* s_in = s_mem;
  u16* s_w  = s_mem + 17920;

  const int tid = threadIdx.x;
  const int bid = ((int)blockIdx.x & 7) * 128 + ((int)blockIdx.x >> 3); // 1024
  const int n = bid >> 7;
  const int oy = (bid >> 2) & 31;
  const int xg = bid & 3;

  const u16* src = cla + (ptrdiff_t)((size_t)n * IMG_CL)
                       + (ptrdiff_t)(8 * oy - 2) * IWCH + (64 * xg - 2) * CH;
  #pragma unroll
  for (int k = 0; k < 9; ++k) {
    int i = tid + (k << 8);
    if (i < 2240) {
      int r = i / 320, o = i - r * 320;
      GLDS16(src + (ptrdiff_t)r * IWCH + o * 8, s_in + i * 8);
    }
  }
  #pragma unroll
  for (int k = 0; k < 8; ++k) {
    int i = tid + (k << 8);
    if (i < 1840) GLDS16(wsc + i * 8, s_w + i * 8);
  }
  __syncthreads();

  const int w = tid >> 6;
  const int l = tid & 63;
  const int g = l >> 4;
  const int m = l & 15;

  const int p0 = m;
  const int p1 = (m < 8) ? 16 + m : 23;
  const int rb0 = 8 * (p0 / 3) + 2 * (p0 % 3);
  const int rb1 = 8 * (p1 / 3) + 2 * (p1 % 3);

  f32x4 acc[2][3];
  #pragma unroll
  for (int mt = 0; mt < 2; ++mt)
    #pragma unroll
    for (int tt = 0; tt < 3; ++tt) acc[mt][tt] = (f32x4){0.f, 0.f, 0.f, 0.f};

  if (w < 3) {
    #pragma unroll
    for (int s = 0; s < 12; ++s) {
      const int dy = s >> 2;
      const int c = ((s & 3) << 2) + g;
      int dx, icb;
      if (c >= 15)      { dx = 0; icb = 0; }
      else if (c >= 10) { dx = 2; icb = (c - 10) * 8; }
      else if (c >= 5)  { dx = 1; icb = (c - 5) * 8; }
      else              { dx = 0; icb = c * 8; }
      const int rowb = (2 * w + dy) * 2560;
      bf16x8 a0 = *(const bf16x8*)(s_in + rowb + (rb0 + dx) * CH + icb);
      bf16x8 a1 = *(const bf16x8*)(s_in + rowb + (rb1 + dx) * CH + icb);

      const u16* wrow = s_w + ((c == 15) ? 45 * 320 : (dy * 15 + c) * 320);
      bf16x8 b0 = *(const bf16x8*)(wrow + m * 8);
      bf16x8 b1 = *(const bf16x8*)(wrow + (m + 16) * 8);
      bf16x8 b2 = *(const bf16x8*)(wrow + (m >= 8 ? 312 : (m + 32) * 8));

      acc[0][0] = __builtin_amdgcn_mfma_f32_16x16x32_bf16(b0, a0, acc[0][0], 0, 0, 0);
      acc[1][0] = __builtin_amdgcn_mfma_f32_16x16x32_bf16(b0, a1, acc[1][0], 0, 0, 0);
      acc[0][1] = __builtin_amdgcn_mfma_f32_16x16x32_bf16(b1, a0, acc[0][1], 0, 0, 0);
      acc[1][1] = __builtin_amdgcn_mfma_f32_16x16x32_bf16(b1, a1, acc[1][1], 0, 0, 0);
      acc[0][2] = __builtin_amdgcn_mfma_f32_16x16x32_bf16(b2, a0, acc[0][2], 0, 0, 0);
      acc[1][2] = __builtin_amdgcn_mfma_f32_16x16x32_bf16(b2, a1, acc[1][2], 0, 0, 0);
    }
  }

  __syncthreads();
  if (w == 3) return;

  char* so = (char*)s_w + w * 2048;
  float4 bv[3];
  bv[0] = *(const float4*)(bias + 4 * g);
  bv[1] = *(const float4*)(bias + 16 + 4 * g);
  bv[2] = (g < 2) ? *(const float4*)(bias + 32 + 4 * g)
                  : make_float4(0.f, 0.f, 0.f, 0.f);
  #pragma unroll
  for (int tt = 0; tt < 3; ++tt) {
    if (tt == 2 && g >= 2) continue;
    #pragma unroll
    for (int mt = 0; mt < 2; ++mt) {
      const int p = mt * 16 + m;
      if (p >= 24) continue;
      float v[4];
      #pragma unroll
      for (int i = 0; i < 4; ++i)
        v[i] = actf(acc[mt][tt][i] + ((const float*)&bv[tt])[i], 1);
      uint2 pk;
      pk.x = pkbf(v[0], v[1]);
      pk.y = pkbf(v[2], v[3]);
      int byt = p * 80 + (16 * tt + 4 * g) * 2;
      byt ^= ((p >> 3) & 7) << 4;
      *(uint2*)(so + byt) = pk;
    }
  }

  const int yi = oy * 3 + w;
  const int y = 8 * oy - 2 + 2 * w;
  const bool rowinv = (y < 0);
  #pragma unroll
  for (int pass = 0; pass < 2; ++pass) {
    int j = pass * 64 + l;
    if (j >= 120) continue;
    int p = j / 5, oct = j % 5;
    int byt = p * 80 + oct * 16;
    byt ^= ((p >> 3) & 7) << 4;
    uint4 d = *(const uint4*)(so + byt);
    int x = 64 * xg + 8 * (p / 3) + 2 * (p % 3) - 2;
    if (rowinv || x < 0) {
      d = (uint4){0u, 0u, 0u, 0u};
    } else {
      const u16* rp = cla + (size_t)n * IMG_CL
                    + ((size_t)(y + 1) * IW + (x + 1)) * CH + oct * 8;
      uint4 rv = *(const uint4*)rp;
      d.x = addbf2(d.x, rv.x); d.y = addbf2(d.y, rv.y);
      d.z = addbf2(d.z, rv.z); d.w = addbf2(d.w, rv.w);
    }
    *(uint4*)(ddc + (((size_t)(n * 96 + yi)) * 96 + 24 * xg + p) * CH + oct * 8) = d;
  }
}

// ---- FUSED depthwise conv + per-8x8 iDCT; block = one (n,c) plane --------
__global__ __launch_bounds__(256)
void dwidct_k(const u16* __restrict__ ddc, const float* __restrict__ w,
              const float* __restrict__ b, float* __restrict__ out)
{
  __shared__ float s_p[32 * 33];
  __shared__ float ctab[8];
  const int nc = blockIdx.x;               // n*40 + c
  const int c = nc % CH, n = nc / CH;
  const int t = threadIdx.x;
  if (t < 8) {
    const float c_[8] = {1.f, 0.70710678118654752f, 0.f, -0.70710678118654752f,
                         -1.f, -0.70710678118654752f, 0.f, 0.70710678118654752f};
    ctab[t] = c_[t];
  }
  float wv[9];
  #pragma unroll
  for (int i = 0; i < 9; ++i) wv[i] = w[c * 9 + i];
  const float bvv = b[c];

  #pragma unroll
  for (int q = 0; q < 4; ++q) {
    int p = t + (q << 8);
    int ox = p & 31, oy = p >> 5;
    const u16* base = ddc + (((size_t)(n * 96 + oy * 3)) * 96 + ox * 3) * CH + c;
    float acc = bvv;
    #pragma unroll
    for (int dyi = 0; dyi < 3; ++dyi)
      #pragma unroll
      for (int dxi = 0; dxi < 3; ++dxi)
        acc += wv[dyi * 3 + dxi] * b2f(base[((size_t)dyi * 96 + dxi) * CH]);
    s_p[oy * 33 + ox] = acc;
  }
  __syncthreads();
  #pragma unroll
  for (int q = 0; q < 4; ++q) {
    int p = t + (q << 8);
    int ox = p & 31, oy = p >> 5;
    int k = oy & 7, lq = ox & 7;
    const float* ip = &s_p[(oy & ~7) * 33 + (ox & ~7)];
    float acc = 0.f;
    #pragma unroll
    for (int mm = 0; mm < 8; ++mm) {
      float rk = ctab[(k * mm) & 7];
      float s = 0.f;
      #pragma unroll
      for (int nn = 0; nn < 8; ++nn)
        s += ctab[(lq * nn) & 7] * ip[mm * 33 + nn];
      acc += rk * s;
    }
    out[((size_t)nc << 10) + p] = acc * 0.125f;
  }
}

// ---- MFMA 1x1 conv + sigmoid + bilinear(32->256) multiply; cl bf16 -------
__global__ __launch_bounds__(256)
void wgtmul_k(const u16* __restrict__ t1cl, const u16* __restrict__ wt3,
              const float* __restrict__ b3, const float* __restrict__ dct,
              u16* __restrict__ outcl)
{
  __shared__ float s_yw[40 * 33];
  __shared__ u16 s_out[4 * 3072];

  const int q8 = (int)gridDim.x >> 3;
  const int bid = ((int)blockIdx.x & 7) * q8 + ((int)blockIdx.x >> 3);
  const int n = bid >> 8;
  const int y = bid & 255;
  const int tid = threadIdx.x;

  float sy = (y + 0.5f) * 0.125f - 0.5f;
  float yq = floorf(sy);
  float fy = sy - yq;
  int y0c = max((int)yq, 0), y1c = min((int)yq + 1, 31);

  for (int i = tid; i < 1280; i += 256) {
    int oc = i >> 5, c = i & 31;
    const float* sp = dct + ((size_t)(n * CH + oc) << 10);
    s_yw[oc * 33 + c] = (1.f - fy) * sp[y0c * 32 + c] + fy * sp[y1c * 32 + c];
  }
  __syncthreads();

  const int w = tid >> 6;
  const int l = tid & 63;
  const int g = l >> 4;
  const int m = l & 15;
  const int xb = w << 6;

  const u16* tp = t1cl + (size_t)n * IMG_CL + ((size_t)(y + 1) * IW + 1) * CH;

  f32x4 acc[4][3];
  #pragma unroll
  for (int xt = 0; xt < 4; ++xt)
    #pragma unroll
    for (int t = 0; t < 3; ++t) acc[xt][t] = (f32x4){0.f, 0.f, 0.f, 0.f};

  #pragma unroll
  for (int xt = 0; xt < 4; ++xt) {
    const u16* ap = tp + (size_t)(xb + xt * 16 + m) * CH;
    bf16x8 a0 = *(const bf16x8*)(ap + 8 * g);
    bf16x8 a1 = *(const bf16x8*)(ap + 32 + 8 * g);
    #pragma unroll
    for (int t = 0; t < 3; ++t) {
      bf16x8 b0 = *(const bf16x8*)(wt3 + (m + 16 * t) * 384 + 8 * g);
      bf16x8 b1 = *(const bf16x8*)(wt3 + (m + 16 * t) * 384 + 32 + 8 * g);
      acc[xt][t] = __builtin_amdgcn_mfma_f32_16x16x32_bf16(b0, a0, acc[xt][t], 0, 0, 0);
      acc[xt][t] = __builtin_amdgcn_mfma_f32_16x16x32_bf16(b1, a1, acc[xt][t], 0, 0, 0);
    }
  }

  u16* so = s_out + w * 3072;
  float4 bv[3];
  bv[0] = *(const float4*)(b3 + 4 * g);
  bv[1] = *(const float4*)(b3 + 16 + 4 * g);
  bv[2] = (g < 2) ? *(const float4*)(b3 + 32 + 4 * g) : make_float4(0.f, 0.f, 0.f, 0.f);
  #pragma unroll
  for (int t = 0; t < 3; ++t) {
    if (t == 2 && g >= 2) continue;
    #pragma unroll
    for (int xt = 0; xt < 4; ++xt) {
      const int pxl = xt * 16 + m;
      const int px = xb + pxl;
      float sx = (px + 0.5f) * 0.125f - 0.5f;
      float xq = floorf(sx);
      float fx = sx - xq;
      int x0c = max((int)xq, 0), x1c = min((int)xq + 1, 31);
      float r4[4];
      #pragma unroll
      for (int i = 0; i < 4; ++i) {
        int oc = 16 * t + 4 * g + i;
        float wgt = 1.f / (1.f + __expf(-(acc[xt][t][i] + ((const float*)&bv[t])[i])));
        float bil = (1.f - fx) * s_yw[oc * 33 + x0c] + fx * s_yw[oc * 33 + x1c];
        r4[i] = wgt * bil;
      }
      uint2 pk;
      pk.x = pkbf(r4[0], r4[1]);
      pk.y = pkbf(r4[2], r4[3]);
      int byt = pxl * 80 + (16 * t + 4 * g) * 2;
      byt ^= ((pxl >> 3) & 7) << 4;
      *(uint2*)((char*)so + byt) = pk;
    }
  }
  const size_t rowu = (size_t)n * IMG_CL + ((size_t)(y + 1) * IW + (xb + 1)) * CH;
  #pragma unroll
  for (int q = 0; q < 5; ++q) {
    int byt = l * 80 + q * 16;
    byt ^= ((l >> 3) & 7) << 4;
    uint4 d = *(const uint4*)((const char*)so + byt);
    *(uint4*)(outcl + rowu + (size_t)l * 40 + q * 8) = d;
  }
}

extern "C" void kernel_launch(void* const* d_in, const int* in_sizes, int n_in,
                              void* d_out, int out_size, void* d_ws, size_t ws_size,
                              hipStream_t stream)
{
  const float* x       = (const float*)d_in[0];
  const float* conv_w  = (const float*)d_in[1];
  const float* conv_b  = (const float*)d_in[2];
  const float* ddct_w  = (const float*)d_in[3];
  const float* ddct_b  = (const float*)d_in[4];
  const float* dctc_w  = (const float*)d_in[5];
  const float* dctc_b  = (const float*)d_in[6];
  const float* w1_w    = (const float*)d_in[7];
  const float* w1_b    = (const float*)d_in[8];
  const float* w3_w    = (const float*)d_in[9];
  const float* w3_b    = (const float*)d_in[10];
  const float* after_w = (const float*)d_in[11];
  const float* after_b = (const float*)d_in[12];

  char* ws = (char*)d_ws;
  const size_t CLB = (size_t)8 * IMG_CL * 2;          // 42,600,960 B
  float* small1 = (float*)ws;                         // 1,310,720 (idct out)
  u16*   wt4    = (u16*)(ws + 1310720);               // 36,864 (w3 rm)
  u16*   wcma   = (u16*)(ws + 1347584);               // 30,720 (after cm)
  u16*   wsc    = (u16*)(ws + 1378304);               // 88,320 (3 compressed)
  u16*   ddc    = (u16*)(ws + 1466624);               // 5,898,240 compact dd
  u16*   cl_a   = (u16*)(ws + 7364864);               // dct_feat, later prod
  u16*   cl_c   = (u16*)(ws + 7364864 + CLB);         // t1

  // 0. weight transforms + cl_a ring zeroing
  prep_w_k<<<305, 256, 0, stream>>>(conv_w, ddct_w, w1_w, after_w, w3_w,
                                    wt4, wcma, wsc);
  ringz_k<<<8 * IW, 256, 0, stream>>>(cl_a);
  // 1+5. dct_feat = gelu(conv1(x)) -> cl_a ; t1 = relu(conv5(x)) -> cl_c
  fconv2p_k<<<2048, 512, 0, stream>>>(x, wsc, wsc + WSC_SET,
                                      conv_b, w1_b, cl_a, cl_c);
  // 2. SPARSE dd at dwconv sample points           -> ddc (compact)
  sconv_k<<<1024, 256, 0, stream>>>(cl_a, wsc + 2 * WSC_SET, ddct_b, ddc);
  // 3+4. depthwise conv + per-block iDCT (fused)   -> small1
  dwidct_k<<<320, 256, 0, stream>>>(ddc, dctc_w, dctc_b, small1);
  // 6. prod = sigmoid(1x1(t1)) * bilinear(idct)    -> cl_a (dct_feat dead)
  wgtmul_k<<<2048, 256, 0, stream>>>(cl_c, wt4, w3_b, small1, cl_a);
  // 7. out = conv(prod, after)                     -> d_out fp32 planar
  convl_k<<<2048, 512, 0, stream>>>(cl_a, wcma, after_b, (float*)d_out);
}

// Round 20
// 166.906 us; speedup vs baseline: 1.1241x; 1.1241x over previous
//
#include <hip/hip_runtime.h>

typedef unsigned short u16;
typedef unsigned int u32;
typedef __attribute__((ext_vector_type(8))) short bf16x8;
typedef __attribute__((ext_vector_type(4))) float f32x4;

#define CH 40
#define IW 258                   // ring-padded width (256 + 2)
#define IWCH (IW * CH)           // 10320
#define IMG_CL (IW * IW * CH)    // u16 elements per image, channel-last padded
#define WT_SET (48 * 384)        // u16: w3 row-major set (wgtmul)
#define WCM_SET (48 * 40 * 8)    // u16: after_w chunk-major set (conv7) = 15360
#define WSC_SET (46 * 40 * 8)    // u16 compressed set: 45 real + 1 zero = 14720

// NOTE (r18 lesson): global_load_lds dest is wave-uniform-base + lane*16;
// only use it in trailing-predicated single-branch form (first active lane 0).
#define GLDS16(g, l) __builtin_amdgcn_global_load_lds( \
    (const __attribute__((address_space(1))) void*)(g), \
    (__attribute__((address_space(3))) void*)(l), 16, 0, 0)

__device__ __forceinline__ float b2f(u16 u) {
  union { u32 i; float f; } v; v.i = ((u32)u) << 16; return v.f;
}
// HW packed f32->bf16 (RNE)
__device__ __forceinline__ u32 pkbf(float lo, float hi) {
  u32 r;
  asm("v_cvt_pk_bf16_f32 %0, %1, %2" : "=v"(r) : "v"(lo), "v"(hi));
  return r;
}
__device__ __forceinline__ u16 f2b(float f) {
  union { float f; u32 i; } v; v.f = f;
  u32 r = v.i + 0x7fffu + ((v.i >> 16) & 1u);
  return (u16)(r >> 16);
}
__device__ __forceinline__ u32 addbf2(u32 a, u32 b) {
  union { u32 i; float f; } lo_a, lo_b, hi_a, hi_b;
  lo_a.i = a << 16; lo_b.i = b << 16;
  hi_a.i = a & 0xffff0000u; hi_b.i = b & 0xffff0000u;
  return pkbf(lo_a.f + lo_b.f, hi_a.f + hi_b.f);
}
// tanh-approx gelu (validated r10)
__device__ __forceinline__ float actf(float t, int ACT) {
  if (ACT == 1) {
    float u2 = t * (1.5957691216057308f + 0.07135481627000862f * t * t);
    float e = __expf(u2);
    return t - t / (e + 1.f);
  }
  if (ACT == 2) return fmaxf(t, 0.f);
  return t;
}

// ---- weights: w3 rm + after cm + compressed 46-chunk x3 ------------------
__global__ __launch_bounds__(256)
void prep_w_k(const float* __restrict__ w0, const float* __restrict__ w1,
              const float* __restrict__ w2, const float* __restrict__ w3,
              const float* __restrict__ w4, u16* __restrict__ wt4,
              u16* __restrict__ wcma, u16* __restrict__ wsc)
{
  int i = blockIdx.x * 256 + threadIdx.x;
  if (i >= WT_SET + WCM_SET + 3 * WSC_SET) return;
  if (i < WT_SET) {
    int k = i % 384;
    int oc = i / 384;
    u16 v = 0;
    if (oc < 40 && k < 40) v = f2b(w4[oc * 40 + k]);
    wt4[i] = v;
  } else if (i < WT_SET + WCM_SET) {
    int j = i - WT_SET;
    int c = j / 320;
    int rem = j - c * 320;
    int oc = rem >> 3;
    int e = rem & 7;
    int k = c * 8 + e;
    int dy = k >> 7;
    int r = k & 127;
    u16 v = 0;
    if (r < 120) {
      int dx = r / 40;
      int ic = r - dx * 40;
      v = f2b(w3[((oc * 40 + ic) * 3 + dy) * 3 + dx]);
    }
    wcma[j] = v;
  } else {
    int j2 = i - WT_SET - WCM_SET;
    int set3 = j2 / WSC_SET;
    int r3 = j2 - set3 * WSC_SET;
    int c2 = r3 / 320;
    int rem = r3 - c2 * 320;
    int oc = rem >> 3;
    int e = rem & 7;
    u16 v = 0;
    if (c2 < 45) {
      int dy = c2 / 15, cc = c2 % 15;
      int dx = cc / 5, icq = cc % 5;
      int ic = icq * 8 + e;
      const float* w = (set3 == 0) ? w0 : (set3 == 1) ? w2 : w1;
      v = f2b(w[((oc * 40 + ic) * 3 + dy) * 3 + dx]);
    }
    wsc[j2] = v;
  }
}

// ---- zero the halo rings of cl_a -----------------------------------------
__global__ __launch_bounds__(256)
void ringz_k(u16* __restrict__ cla)
{
  const int n = blockIdx.x / IW;
  const int yr = blockIdx.x % IW;
  const int t = threadIdx.x;
  const size_t base = (size_t)n * IMG_CL + (size_t)yr * IWCH;
  const uint4 z = {0u, 0u, 0u, 0u};
  if (yr == 0 || yr == IW - 1) {
    for (int i = t; i < IWCH / 8; i += 256) ((uint4*)(cla + base))[i] = z;
    return;
  }
  if (t < 5) {
    ((uint4*)(cla + base))[t] = z;
  } else if (t < 10) {
    ((uint4*)(cla + base + (size_t)(IW - 1) * CH))[t - 5] = z;
  }
}

// ---- fused conv1+conv5, 512 thr / 8 waves (r17-proven, monolithic wts) ---
__global__ __launch_bounds__(512, 2)
void fconv2p_k(const float* __restrict__ xg, const u16* __restrict__ wscA,
               const u16* __restrict__ wscB, const float* __restrict__ biasA,
               const float* __restrict__ biasB, u16* __restrict__ outA,
               u16* __restrict__ outB)
{
  __shared__ __align__(16) u16 s_mem[30560];   // x 15840 + w 14720 = 61120 B
  u16* s_in = s_mem;
  u16* s_w  = s_mem + 15840;                   // weights; reused as restage

  const int tid = threadIdx.x;
  const int bid = ((int)blockIdx.x & 7) * 256 + ((int)blockIdx.x >> 3);
  const int n = bid >> 8;
  const int tb = bid & 255;
  const int y0 = (tb >> 2) << 2;
  const int x0 = (tb & 3) << 6;

  #pragma unroll
  for (int k = 0; k < 4; ++k) {                // wA: 1840 16B chunks
    int i = tid + (k << 9);
    if (i < 1840) GLDS16(wscA + i * 8, s_w + i * 8);
  }
  // stage x tile (6 rows x 66 px x 40 ic), packed-converting
  const float* xsrc = xg + (size_t)n * CH * 65536;
  if (tid < 396) {
    int slot = tid;
    int r = slot / 66, p = slot - r * 66;
    int gy = y0 + r - 1, gx = x0 + p - 1;
    __attribute__((aligned(16))) u32 buf[20];
    if ((unsigned)gy < 256u && (unsigned)gx < 256u) {
      const float* xp = xsrc + (size_t)gy * 256 + gx;
      #pragma unroll
      for (int icp = 0; icp < 20; ++icp)
        buf[icp] = pkbf(xp[(size_t)(2 * icp) * 65536],
                        xp[(size_t)(2 * icp + 1) * 65536]);
    } else {
      #pragma unroll
      for (int icp = 0; icp < 20; ++icp) buf[icp] = 0u;
    }
    u16* dst = s_in + slot * 40;
    #pragma unroll
    for (int q = 0; q < 5; ++q) ((uint4*)dst)[q] = ((const uint4*)buf)[q];
  }
  __syncthreads();

  const int w = tid >> 6;
  const int ry = w >> 1;                       // output row y0+ry
  const int h = w & 1;                         // x half: px (2h..2h+1)*16
  const int l = tid & 63;
  const int g = l >> 4;
  const int m = l & 15;

  f32x4 accA[2][3], accB[2][3];
  #pragma unroll
  for (int xt = 0; xt < 2; ++xt)
    #pragma unroll
    for (int tt = 0; tt < 3; ++tt) {
      accA[xt][tt] = (f32x4){0.f, 0.f, 0.f, 0.f};
      accB[xt][tt] = (f32x4){0.f, 0.f, 0.f, 0.f};
    }

  // ---- K-loop pass A -----------------------------------------------------
  #pragma unroll
  for (int s = 0; s < 12; ++s) {
    const int dy = s >> 2;
    const int c = ((s & 3) << 2) + g;
    int dx, icb;
    if (c >= 15)      { dx = 0; icb = 0; }
    else if (c >= 10) { dx = 2; icb = (c - 10) * 8; }
    else if (c >= 5)  { dx = 1; icb = (c - 5) * 8; }
    else              { dx = 0; icb = c * 8; }
    const int abase = (ry + dy) * (66 * CH) + ((h * 2) * 16 + m + dx) * CH + icb;
    bf16x8 a0 = *(const bf16x8*)(s_in + abase);
    bf16x8 a1 = *(const bf16x8*)(s_in + abase + 16 * CH);
    const u16* wrow = s_w + ((c >= 15) ? 45 * 320 : (dy * 15 + c) * 320);
    bf16x8 b0 = *(const bf16x8*)(wrow + m * 8);
    bf16x8 b1 = *(const bf16x8*)(wrow + (m + 16) * 8);
    bf16x8 b2 = *(const bf16x8*)(wrow + (m >= 8 ? 312 : (m + 32) * 8));
    accA[0][0] = __builtin_amdgcn_mfma_f32_16x16x32_bf16(b0, a0, accA[0][0], 0, 0, 0);
    accA[1][0] = __builtin_amdgcn_mfma_f32_16x16x32_bf16(b0, a1, accA[1][0], 0, 0, 0);
    accA[0][1] = __builtin_amdgcn_mfma_f32_16x16x32_bf16(b1, a0, accA[0][1], 0, 0, 0);
    accA[1][1] = __builtin_amdgcn_mfma_f32_16x16x32_bf16(b1, a1, accA[1][1], 0, 0, 0);
    accA[0][2] = __builtin_amdgcn_mfma_f32_16x16x32_bf16(b2, a0, accA[0][2], 0, 0, 0);
    accA[1][2] = __builtin_amdgcn_mfma_f32_16x16x32_bf16(b2, a1, accA[1][2], 0, 0, 0);
  }

  __syncthreads();                             // all waves done reading wA
  #pragma unroll
  for (int k = 0; k < 4; ++k) {                // wB into same region
    int i = tid + (k << 9);
    if (i < 1840) GLDS16(wscB + i * 8, s_w + i * 8);
  }
  __syncthreads();                             // wB ready (vmcnt drained)

  // ---- K-loop pass B -----------------------------------------------------
  #pragma unroll
  for (int s = 0; s < 12; ++s) {
    const int dy = s >> 2;
    const int c = ((s & 3) << 2) + g;
    int dx, icb;
    if (c >= 15)      { dx = 0; icb = 0; }
    else if (c >= 10) { dx = 2; icb = (c - 10) * 8; }
    else if (c >= 5)  { dx = 1; icb = (c - 5) * 8; }
    else              { dx = 0; icb = c * 8; }
    const int abase = (ry + dy) * (66 * CH) + ((h * 2) * 16 + m + dx) * CH + icb;
    bf16x8 a0 = *(const bf16x8*)(s_in + abase);
    bf16x8 a1 = *(const bf16x8*)(s_in + abase + 16 * CH);
    const u16* wrow = s_w + ((c >= 15) ? 45 * 320 : (dy * 15 + c) * 320);
    bf16x8 b0 = *(const bf16x8*)(wrow + m * 8);
    bf16x8 b1 = *(const bf16x8*)(wrow + (m + 16) * 8);
    bf16x8 b2 = *(const bf16x8*)(wrow + (m >= 8 ? 312 : (m + 32) * 8));
    accB[0][0] = __builtin_amdgcn_mfma_f32_16x16x32_bf16(b0, a0, accB[0][0], 0, 0, 0);
    accB[1][0] = __builtin_amdgcn_mfma_f32_16x16x32_bf16(b0, a1, accB[1][0], 0, 0, 0);
    accB[0][1] = __builtin_amdgcn_mfma_f32_16x16x32_bf16(b1, a0, accB[0][1], 0, 0, 0);
    accB[1][1] = __builtin_amdgcn_mfma_f32_16x16x32_bf16(b1, a1, accB[1][1], 0, 0, 0);
    accB[0][2] = __builtin_amdgcn_mfma_f32_16x16x32_bf16(b2, a0, accB[0][2], 0, 0, 0);
    accB[1][2] = __builtin_amdgcn_mfma_f32_16x16x32_bf16(b2, a1, accB[1][2], 0, 0, 0);
  }

  __syncthreads();                             // all reads of s_w/s_in done

  float4 bvA[3], bvB[3];
  bvA[0] = *(const float4*)(biasA + 4 * g);
  bvA[1] = *(const float4*)(biasA + 16 + 4 * g);
  bvA[2] = (g < 2) ? *(const float4*)(biasA + 32 + 4 * g) : make_float4(0.f, 0.f, 0.f, 0.f);
  bvB[0] = *(const float4*)(biasB + 4 * g);
  bvB[1] = *(const float4*)(biasB + 16 + 4 * g);
  bvB[2] = (g < 2) ? *(const float4*)(biasB + 32 + 4 * g) : make_float4(0.f, 0.f, 0.f, 0.f);

  // row-shared restage regions: row ry -> s_w + ry*5120 bytes
  char* so = (char*)s_w + ry * 5120;
  const int rdrow = tid >> 7;                  // readback: 128 threads per row
  const int l2 = tid & 127;
  const size_t rowu_rd = (size_t)n * IMG_CL
                       + ((size_t)(y0 + rdrow + 1) * IW + (x0 + 1)) * CH;

  // ---- pass A: restage -> barrier -> readback ----------------------------
  #pragma unroll
  for (int tt = 0; tt < 3; ++tt) {
    if (tt == 2 && g >= 2) continue;
    #pragma unroll
    for (int xt = 0; xt < 2; ++xt) {
      const int pxl = (2 * h + xt) * 16 + m;
      float v[4];
      #pragma unroll
      for (int i = 0; i < 4; ++i)
        v[i] = actf(accA[xt][tt][i] + ((const float*)&bvA[tt])[i], 1);
      uint2 pk;
      pk.x = pkbf(v[0], v[1]);
      pk.y = pkbf(v[2], v[3]);
      int byt = pxl * 80 + (16 * tt + 4 * g) * 2;
      byt ^= ((pxl >> 3) & 7) << 4;
      *(uint2*)(so + byt) = pk;
    }
  }
  __syncthreads();
  {
    const char* ro = (const char*)s_w + rdrow * 5120;
    #pragma unroll
    for (int pass = 0; pass < 3; ++pass) {
      int j = l2 + (pass << 7);
      if (j < 320) {
        int px = j / 5, oct = j % 5;
        int byt = px * 80 + oct * 16;
        byt ^= ((px >> 3) & 7) << 4;
        uint4 d = *(const uint4*)(ro + byt);
        *(uint4*)(outA + rowu_rd + (size_t)px * 40 + oct * 8) = d;
      }
    }
  }
  __syncthreads();

  // ---- pass B ------------------------------------------------------------
  #pragma unroll
  for (int tt = 0; tt < 3; ++tt) {
    if (tt == 2 && g >= 2) continue;
    #pragma unroll
    for (int xt = 0; xt < 2; ++xt) {
      const int pxl = (2 * h + xt) * 16 + m;
      float v[4];
      #pragma unroll
      for (int i = 0; i < 4; ++i)
        v[i] = actf(accB[xt][tt][i] + ((const float*)&bvB[tt])[i], 2);
      uint2 pk;
      pk.x = pkbf(v[0], v[1]);
      pk.y = pkbf(v[2], v[3]);
      int byt = pxl * 80 + (16 * tt + 4 * g) * 2;
      byt ^= ((pxl >> 3) & 7) << 4;
      *(uint2*)(so + byt) = pk;
    }
  }
  __syncthreads();
  {
    const char* ro = (const char*)s_w + rdrow * 5120;
    #pragma unroll
    for (int pass = 0; pass < 3; ++pass) {
      int j = l2 + (pass << 7);
      if (j < 320) {
        int px = j / 5, oct = j % 5;
        int byt = px * 80 + oct * 16;
        byt ^= ((px >> 3) & 7) << 4;
        uint4 d = *(const uint4*)(ro + byt);
        *(uint4*)(outB + rowu_rd + (size_t)px * 40 + oct * 8) = d;
      }
    }
  }
}

// ---- conv7: all-LDS MFMA conv 3x3, planar f32 out (r17-proven) -----------
__global__ __launch_bounds__(512, 2)
void convl_k(const u16* __restrict__ incl, const u16* __restrict__ wcm,
             const float* __restrict__ bias, float* __restrict__ outp)
{
  __shared__ __align__(16) u16 s_mem[31200];   // input 15840 + weights 15360
  u16* s_in = s_mem;
  u16* s_w  = s_mem + 15840;

  const int tid = threadIdx.x;
  const int bid = ((int)blockIdx.x & 7) * 256 + ((int)blockIdx.x >> 3);
  const int n = bid >> 8;
  const int tb = bid & 255;
  const int y0 = (tb >> 2) << 2;
  const int x0 = (tb & 3) << 6;

  const u16* src = incl + (size_t)n * IMG_CL + ((size_t)y0 * IW + x0) * CH;
  #pragma unroll
  for (int k = 0; k < 4; ++k) {
    int i = tid + (k << 9);
    if (i < 1980) {
      int r = i / 330, o = i - r * 330;
      GLDS16(src + (size_t)r * IWCH + o * 8, s_in + i * 8);
    }
  }
  #pragma unroll
  for (int k = 0; k < 4; ++k) {
    int i = tid + (k << 9);
    if (i < 1920) GLDS16(wcm + i * 8, s_w + i * 8);
  }
  __syncthreads();

  const int w = tid >> 6;
  const int ry = w >> 1;
  const int h = w & 1;
  const int l = tid & 63;
  const int g = l >> 4;
  const int m = l & 15;

  f32x4 acc[2][3];
  #pragma unroll
  for (int xt = 0; xt < 2; ++xt)
    #pragma unroll
    for (int tt = 0; tt < 3; ++tt) acc[xt][tt] = (f32x4){0.f, 0.f, 0.f, 0.f};

  #pragma unroll
  for (int s = 0; s < 12; ++s) {
    const int dy = s >> 2;
    const int c = ((s & 3) << 2) + g;
    int dx, icb;
    if (c >= 15)      { dx = 0; icb = 0; }
    else if (c >= 10) { dx = 2; icb = (c - 10) * 8; }
    else if (c >= 5)  { dx = 1; icb = (c - 5) * 8; }
    else              { dx = 0; icb = c * 8; }
    const int abase = (ry + dy) * (66 * CH) + ((h * 2) * 16 + m + dx) * CH + icb;
    bf16x8 a0 = *(const bf16x8*)(s_in + abase);
    bf16x8 a1 = *(const bf16x8*)(s_in + abase + 16 * CH);

    const int ch = (s << 2) + g;
    const u16* wrow = s_w + ch * 320;
    bf16x8 b0 = *(const bf16x8*)(wrow + m * 8);
    bf16x8 b1 = *(const bf16x8*)(wrow + (m + 16) * 8);
    bf16x8 b2 = *(const bf16x8*)(wrow + (m >= 8 ? 312 : (m + 32) * 8));

    acc[0][0] = __builtin_amdgcn_mfma_f32_16x16x32_bf16(a0, b0, acc[0][0], 0, 0, 0);
    acc[1][0] = __builtin_amdgcn_mfma_f32_16x16x32_bf16(a1, b0, acc[1][0], 0, 0, 0);
    acc[0][1] = __builtin_amdgcn_mfma_f32_16x16x32_bf16(a0, b1, acc[0][1], 0, 0, 0);
    acc[1][1] = __builtin_amdgcn_mfma_f32_16x16x32_bf16(a1, b1, acc[1][1], 0, 0, 0);
    acc[0][2] = __builtin_amdgcn_mfma_f32_16x16x32_bf16(a0, b2, acc[0][2], 0, 0, 0);
    acc[1][2] = __builtin_amdgcn_mfma_f32_16x16x32_bf16(a1, b2, acc[1][2], 0, 0, 0);
  }

  const int y = y0 + ry;
  const float bv0 = bias[m];
  const float bv1 = bias[m + 16];
  const float bv2 = (m < 8) ? bias[m + 32] : 0.f;
  #pragma unroll
  for (int tt = 0; tt < 3; ++tt) {
    const int oc = m + 16 * tt;
    if (tt == 2 && m >= 8) continue;
    const float bv = (tt == 0) ? bv0 : (tt == 1) ? bv1 : bv2;
    #pragma unroll
    for (int xt = 0; xt < 2; ++xt) {
      const int xb = x0 + (2 * h + xt) * 16 + 4 * g;
      float v[4];
      #pragma unroll
      for (int i = 0; i < 4; ++i) v[i] = acc[xt][tt][i] + bv;
      *(float4*)(outp + (((size_t)(n * CH + oc)) << 16) + ((size_t)y << 8) + xb)
          = make_float4(v[0], v[1], v[2], v[3]);
    }
  }
}

// ---- SPARSE conv2 (r13-verified) -----------------------------------------
__global__ __launch_bounds__(256, 2)
void sconv_k(const u16* __restrict__ cla, const u16* __restrict__ wsc,
             const float* __restrict__ bias, u16* __restrict__ ddc)
{
  __shared__ __align__(16) u16 s_mem[32640];   // s_in 17920 + s_w 14720
  u16* s_in = s_mem;
  u16* s_w  = s_mem + 17920;

  const int tid = threadIdx.x;
  const int bid = ((int)blockIdx.x & 7) * 128 + ((int)blockIdx.x >> 3); // 1024
  const int n = bid >> 7;
  const int oy = (bid >> 2) & 31;
  const int xg = bid & 3;

  const u16* src = cla + (ptrdiff_t)((size_t)n * IMG_CL)
                       + (ptrdiff_t)(8 * oy - 2) * IWCH + (64 * xg - 2) * CH;
  #pragma unroll
  for (int k = 0; k < 9; ++k) {
    int i = tid + (k << 8);
    if (i < 2240) {
      int r = i / 320, o = i - r * 320;
      GLDS16(src + (ptrdiff_t)r * IWCH + o * 8, s_in + i * 8);
    }
  }
  #pragma unroll
  for (int k = 0; k < 8; ++k) {
    int i = tid + (k << 8);
    if (i < 1840) GLDS16(wsc + i * 8, s_w + i * 8);
  }
  __syncthreads();

  const int w = tid >> 6;
  const int l = tid & 63;
  const int g = l >> 4;
  const int m = l & 15;

  const int p0 = m;
  const int p1 = (m < 8) ? 16 + m : 23;
  const int rb0 = 8 * (p0 / 3) + 2 * (p0 % 3);
  const int rb1 = 8 * (p1 / 3) + 2 * (p1 % 3);

  f32x4 acc[2][3];
  #pragma unroll
  for (int mt = 0; mt < 2; ++mt)
    #pragma unroll
    for (int tt = 0; tt < 3; ++tt) acc[mt][tt] = (f32x4){0.f, 0.f, 0.f, 0.f};

  if (w < 3) {
    #pragma unroll
    for (int s = 0; s < 12; ++s) {
      const int dy = s >> 2;
      const int c = ((s & 3) << 2) + g;
      int dx, icb;
      if (c >= 15)      { dx = 0; icb = 0; }
      else if (c >= 10) { dx = 2; icb = (c - 10) * 8; }
      else if (c >= 5)  { dx = 1; icb = (c - 5) * 8; }
      else              { dx = 0; icb = c * 8; }
      const int rowb = (2 * w + dy) * 2560;
      bf16x8 a0 = *(const bf16x8*)(s_in + rowb + (rb0 + dx) * CH + icb);
      bf16x8 a1 = *(const bf16x8*)(s_in + rowb + (rb1 + dx) * CH + icb);

      const u16* wrow = s_w + ((c == 15) ? 45 * 320 : (dy * 15 + c) * 320);
      bf16x8 b0 = *(const bf16x8*)(wrow + m * 8);
      bf16x8 b1 = *(const bf16x8*)(wrow + (m + 16) * 8);
      bf16x8 b2 = *(const bf16x8*)(wrow + (m >= 8 ? 312 : (m + 32) * 8));

      acc[0][0] = __builtin_amdgcn_mfma_f32_16x16x32_bf16(b0, a0, acc[0][0], 0, 0, 0);
      acc[1][0] = __builtin_amdgcn_mfma_f32_16x16x32_bf16(b0, a1, acc[1][0], 0, 0, 0);
      acc[0][1] = __builtin_amdgcn_mfma_f32_16x16x32_bf16(b1, a0, acc[0][1], 0, 0, 0);
      acc[1][1] = __builtin_amdgcn_mfma_f32_16x16x32_bf16(b1, a1, acc[1][1], 0, 0, 0);
      acc[0][2] = __builtin_amdgcn_mfma_f32_16x16x32_bf16(b2, a0, acc[0][2], 0, 0, 0);
      acc[1][2] = __builtin_amdgcn_mfma_f32_16x16x32_bf16(b2, a1, acc[1][2], 0, 0, 0);
    }
  }

  __syncthreads();
  if (w == 3) return;

  char* so = (char*)s_w + w * 2048;
  float4 bv[3];
  bv[0] = *(const float4*)(bias + 4 * g);
  bv[1] = *(const float4*)(bias + 16 + 4 * g);
  bv[2] = (g < 2) ? *(const float4*)(bias + 32 + 4 * g)
                  : make_float4(0.f, 0.f, 0.f, 0.f);
  #pragma unroll
  for (int tt = 0; tt < 3; ++tt) {
    if (tt == 2 && g >= 2) continue;
    #pragma unroll
    for (int mt = 0; mt < 2; ++mt) {
      const int p = mt * 16 + m;
      if (p >= 24) continue;
      float v[4];
      #pragma unroll
      for (int i = 0; i < 4; ++i)
        v[i] = actf(acc[mt][tt][i] + ((const float*)&bv[tt])[i], 1);
      uint2 pk;
      pk.x = pkbf(v[0], v[1]);
      pk.y = pkbf(v[2], v[3]);
      int byt = p * 80 + (16 * tt + 4 * g) * 2;
      byt ^= ((p >> 3) & 7) << 4;
      *(uint2*)(so + byt) = pk;
    }
  }

  const int yi = oy * 3 + w;
  const int y = 8 * oy - 2 + 2 * w;
  const bool rowinv = (y < 0);
  #pragma unroll
  for (int pass = 0; pass < 2; ++pass) {
    int j = pass * 64 + l;
    if (j >= 120) continue;
    int p = j / 5, oct = j % 5;
    int byt = p * 80 + oct * 16;
    byt ^= ((p >> 3) & 7) << 4;
    uint4 d = *(const uint4*)(so + byt);
    int x = 64 * xg + 8 * (p / 3) + 2 * (p % 3) - 2;
    if (rowinv || x < 0) {
      d = (uint4){0u, 0u, 0u, 0u};
    } else {
      const u16* rp = cla + (size_t)n * IMG_CL
                    + ((size_t)(y + 1) * IW + (x + 1)) * CH + oct * 8;
      uint4 rv = *(const uint4*)rp;
      d.x = addbf2(d.x, rv.x); d.y = addbf2(d.y, rv.y);
      d.z = addbf2(d.z, rv.z); d.w = addbf2(d.w, rv.w);
    }
    *(uint4*)(ddc + (((size_t)(n * 96 + yi)) * 96 + 24 * xg + p) * CH + oct * 8) = d;
  }
}

// ---- FUSED depthwise conv + per-8x8 iDCT; block = one (n,c) plane --------
__global__ __launch_bounds__(256)
void dwidct_k(const u16* __restrict__ ddc, const float* __restrict__ w,
              const float* __restrict__ b, float* __restrict__ out)
{
  __shared__ float s_p[32 * 33];
  __shared__ float ctab[8];
  const int nc = blockIdx.x;               // n*40 + c
  const int c = nc % CH, n = nc / CH;
  const int t = threadIdx.x;
  if (t < 8) {
    const float c_[8] = {1.f, 0.70710678118654752f, 0.f, -0.70710678118654752f,
                         -1.f, -0.70710678118654752f, 0.f, 0.70710678118654752f};
    ctab[t] = c_[t];
  }
  float wv[9];
  #pragma unroll
  for (int i = 0; i < 9; ++i) wv[i] = w[c * 9 + i];
  const float bvv = b[c];

  #pragma unroll
  for (int q = 0; q < 4; ++q) {
    int p = t + (q << 8);
    int ox = p & 31, oy = p >> 5;
    const u16* base = ddc + (((size_t)(n * 96 + oy * 3)) * 96 + ox * 3) * CH + c;
    float acc = bvv;
    #pragma unroll
    for (int dyi = 0; dyi < 3; ++dyi)
      #pragma unroll
      for (int dxi = 0; dxi < 3; ++dxi)
        acc += wv[dyi * 3 + dxi] * b2f(base[((size_t)dyi * 96 + dxi) * CH]);
    s_p[oy * 33 + ox] = acc;
  }
  __syncthreads();
  #pragma unroll
  for (int q = 0; q < 4; ++q) {
    int p = t + (q << 8);
    int ox = p & 31, oy = p >> 5;
    int k = oy & 7, lq = ox & 7;
    const float* ip = &s_p[(oy & ~7) * 33 + (ox & ~7)];
    float acc = 0.f;
    #pragma unroll
    for (int mm = 0; mm < 8; ++mm) {
      float rk = ctab[(k * mm) & 7];
      float s = 0.f;
      #pragma unroll
      for (int nn = 0; nn < 8; ++nn)
        s += ctab[(lq * nn) & 7] * ip[mm * 33 + nn];
      acc += rk * s;
    }
    out[((size_t)nc << 10) + p] = acc * 0.125f;
  }
}

// ---- MFMA 1x1 conv + sigmoid + bilinear(32->256) multiply; cl bf16 -------
__global__ __launch_bounds__(256)
void wgtmul_k(const u16* __restrict__ t1cl, const u16* __restrict__ wt3,
              const float* __restrict__ b3, const float* __restrict__ dct,
              u16* __restrict__ outcl)
{
  __shared__ float s_yw[40 * 33];
  __shared__ u16 s_out[4 * 3072];

  const int q8 = (int)gridDim.x >> 3;
  const int bid = ((int)blockIdx.x & 7) * q8 + ((int)blockIdx.x >> 3);
  const int n = bid >> 8;
  const int y = bid & 255;
  const int tid = threadIdx.x;

  float sy = (y + 0.5f) * 0.125f - 0.5f;
  float yq = floorf(sy);
  float fy = sy - yq;
  int y0c = max((int)yq, 0), y1c = min((int)yq + 1, 31);

  for (int i = tid; i < 1280; i += 256) {
    int oc = i >> 5, c = i & 31;
    const float* sp = dct + ((size_t)(n * CH + oc) << 10);
    s_yw[oc * 33 + c] = (1.f - fy) * sp[y0c * 32 + c] + fy * sp[y1c * 32 + c];
  }
  __syncthreads();

  const int w = tid >> 6;
  const int l = tid & 63;
  const int g = l >> 4;
  const int m = l & 15;
  const int xb = w << 6;

  const u16* tp = t1cl + (size_t)n * IMG_CL + ((size_t)(y + 1) * IW + 1) * CH;

  f32x4 acc[4][3];
  #pragma unroll
  for (int xt = 0; xt < 4; ++xt)
    #pragma unroll
    for (int t = 0; t < 3; ++t) acc[xt][t] = (f32x4){0.f, 0.f, 0.f, 0.f};

  #pragma unroll
  for (int xt = 0; xt < 4; ++xt) {
    const u16* ap = tp + (size_t)(xb + xt * 16 + m) * CH;
    bf16x8 a0 = *(const bf16x8*)(ap + 8 * g);
    bf16x8 a1 = *(const bf16x8*)(ap + 32 + 8 * g);
    #pragma unroll
    for (int t = 0; t < 3; ++t) {
      bf16x8 b0 = *(const bf16x8*)(wt3 + (m + 16 * t) * 384 + 8 * g);
      bf16x8 b1 = *(const bf16x8*)(wt3 + (m + 16 * t) * 384 + 32 + 8 * g);
      acc[xt][t] = __builtin_amdgcn_mfma_f32_16x16x32_bf16(b0, a0, acc[xt][t], 0, 0, 0);
      acc[xt][t] = __builtin_amdgcn_mfma_f32_16x16x32_bf16(b1, a1, acc[xt][t], 0, 0, 0);
    }
  }

  u16* so = s_out + w * 3072;
  float4 bv[3];
  bv[0] = *(const float4*)(b3 + 4 * g);
  bv[1] = *(const float4*)(b3 + 16 + 4 * g);
  bv[2] = (g < 2) ? *(const float4*)(b3 + 32 + 4 * g) : make_float4(0.f, 0.f, 0.f, 0.f);
  #pragma unroll
  for (int t = 0; t < 3; ++t) {
    if (t == 2 && g >= 2) continue;
    #pragma unroll
    for (int xt = 0; xt < 4; ++xt) {
      const int pxl = xt * 16 + m;
      const int px = xb + pxl;
      float sx = (px + 0.5f) * 0.125f - 0.5f;
      float xq = floorf(sx);
      float fx = sx - xq;
      int x0c = max((int)xq, 0), x1c = min((int)xq + 1, 31);
      float r4[4];
      #pragma unroll
      for (int i = 0; i < 4; ++i) {
        int oc = 16 * t + 4 * g + i;
        float wgt = 1.f / (1.f + __expf(-(acc[xt][t][i] + ((const float*)&bv[t])[i])));
        float bil = (1.f - fx) * s_yw[oc * 33 + x0c] + fx * s_yw[oc * 33 + x1c];
        r4[i] = wgt * bil;
      }
      uint2 pk;
      pk.x = pkbf(r4[0], r4[1]);
      pk.y = pkbf(r4[2], r4[3]);
      int byt = pxl * 80 + (16 * t + 4 * g) * 2;
      byt ^= ((pxl >> 3) & 7) << 4;
      *(uint2*)((char*)so + byt) = pk;
    }
  }
  const size_t rowu = (size_t)n * IMG_CL + ((size_t)(y + 1) * IW + (xb + 1)) * CH;
  #pragma unroll
  for (int q = 0; q < 5; ++q) {
    int byt = l * 80 + q * 16;
    byt ^= ((l >> 3) & 7) << 4;
    uint4 d = *(const uint4*)((const char*)so + byt);
    *(uint4*)(outcl + rowu + (size_t)l * 40 + q * 8) = d;
  }
}

extern "C" void kernel_launch(void* const* d_in, const int* in_sizes, int n_in,
                              void* d_out, int out_size, void* d_ws, size_t ws_size,
                              hipStream_t stream)
{
  const float* x       = (const float*)d_in[0];
  const float* conv_w  = (const float*)d_in[1];
  const float* conv_b  = (const float*)d_in[2];
  const float* ddct_w  = (const float*)d_in[3];
  const float* ddct_b  = (const float*)d_in[4];
  const float* dctc_w  = (const float*)d_in[5];
  const float* dctc_b  = (const float*)d_in[6];
  const float* w1_w    = (const float*)d_in[7];
  const float* w1_b    = (const float*)d_in[8];
  const float* w3_w    = (const float*)d_in[9];
  const float* w3_b    = (const float*)d_in[10];
  const float* after_w = (const float*)d_in[11];
  const float* after_b = (const float*)d_in[12];

  char* ws = (char*)d_ws;
  const size_t CLB = (size_t)8 * IMG_CL * 2;          // 42,600,960 B
  float* small1 = (float*)ws;                         // 1,310,720 (idct out)
  u16*   wt4    = (u16*)(ws + 1310720);               // 36,864 (w3 rm)
  u16*   wcma   = (u16*)(ws + 1347584);               // 30,720 (after cm)
  u16*   wsc    = (u16*)(ws + 1378304);               // 88,320 (3 compressed)
  u16*   ddc    = (u16*)(ws + 1466624);               // 5,898,240 compact dd
  u16*   cl_a   = (u16*)(ws + 7364864);               // dct_feat, later prod
  u16*   cl_c   = (u16*)(ws + 7364864 + CLB);         // t1

  // 0. weight transforms + cl_a ring zeroing
  prep_w_k<<<305, 256, 0, stream>>>(conv_w, ddct_w, w1_w, after_w, w3_w,
                                    wt4, wcma, wsc);
  ringz_k<<<8 * IW, 256, 0, stream>>>(cl_a);
  // 1+5. dct_feat = gelu(conv1(x)) -> cl_a ; t1 = relu(conv5(x)) -> cl_c
  fconv2p_k<<<2048, 512, 0, stream>>>(x, wsc, wsc + WSC_SET,
                                      conv_b, w1_b, cl_a, cl_c);
  // 2. SPARSE dd at dwconv sample points           -> ddc (compact)
  sconv_k<<<1024, 256, 0, stream>>>(cl_a, wsc + 2 * WSC_SET, ddct_b, ddc);
  // 3+4. depthwise conv + per-block iDCT (fused)   -> small1
  dwidct_k<<<320, 256, 0, stream>>>(ddc, dctc_w, dctc_b, small1);
  // 6. prod = sigmoid(1x1(t1)) * bilinear(idct)    -> cl_a (dct_feat dead)
  wgtmul_k<<<2048, 256, 0, stream>>>(cl_c, wt4, w3_b, small1, cl_a);
  // 7. out = conv(prod, after)                     -> d_out fp32 planar
  convl_k<<<2048, 512, 0, stream>>>(cl_a, wcma, after_b, (float*)d_out);
}

// Round 21
// 157.101 us; speedup vs baseline: 1.1943x; 1.0624x over previous
//
#include <hip/hip_runtime.h>

typedef unsigned short u16;
typedef unsigned int u32;
typedef __attribute__((ext_vector_type(8))) short bf16x8;
typedef __attribute__((ext_vector_type(4))) float f32x4;

#define CH 40
#define IW 258                   // ring-padded width (256 + 2)
#define IWCH (IW * CH)           // 10320
#define IMG_CL (IW * IW * CH)    // u16 elements per image, channel-last padded
#define WT_SET (48 * 384)        // u16: w3 row-major set (wgtmul)
#define WCM_SET (48 * 40 * 8)    // u16: after_w chunk-major set (conv7) = 15360
#define WSC_SET (46 * 40 * 8)    // u16 compressed set: 45 real + 1 zero = 14720

// NOTE (r18 lesson): global_load_lds dest is wave-uniform-base + lane*16;
// only use it in trailing-predicated single-branch form (first active lane 0).
#define GLDS16(g, l) __builtin_amdgcn_global_load_lds( \
    (const __attribute__((address_space(1))) void*)(g), \
    (__attribute__((address_space(3))) void*)(l), 16, 0, 0)

__device__ __forceinline__ float b2f(u16 u) {
  union { u32 i; float f; } v; v.i = ((u32)u) << 16; return v.f;
}
// HW packed f32->bf16 (RNE)
__device__ __forceinline__ u32 pkbf(float lo, float hi) {
  u32 r;
  asm("v_cvt_pk_bf16_f32 %0, %1, %2" : "=v"(r) : "v"(lo), "v"(hi));
  return r;
}
__device__ __forceinline__ u16 f2b(float f) {
  union { float f; u32 i; } v; v.f = f;
  u32 r = v.i + 0x7fffu + ((v.i >> 16) & 1u);
  return (u16)(r >> 16);
}
__device__ __forceinline__ u32 addbf2(u32 a, u32 b) {
  union { u32 i; float f; } lo_a, lo_b, hi_a, hi_b;
  lo_a.i = a << 16; lo_b.i = b << 16;
  hi_a.i = a & 0xffff0000u; hi_b.i = b & 0xffff0000u;
  return pkbf(lo_a.f + lo_b.f, hi_a.f + hi_b.f);
}
// tanh-approx gelu (validated r10)
__device__ __forceinline__ float actf(float t, int ACT) {
  if (ACT == 1) {
    float u2 = t * (1.5957691216057308f + 0.07135481627000862f * t * t);
    float e = __expf(u2);
    return t - t / (e + 1.f);
  }
  if (ACT == 2) return fmaxf(t, 0.f);
  return t;
}

// ---- weights: w3 rm + after cm + compressed 46-chunk x3 ------------------
__global__ __launch_bounds__(256)
void prep_w_k(const float* __restrict__ w0, const float* __restrict__ w1,
              const float* __restrict__ w2, const float* __restrict__ w3,
              const float* __restrict__ w4, u16* __restrict__ wt4,
              u16* __restrict__ wcma, u16* __restrict__ wsc)
{
  int i = blockIdx.x * 256 + threadIdx.x;
  if (i >= WT_SET + WCM_SET + 3 * WSC_SET) return;
  if (i < WT_SET) {
    int k = i % 384;
    int oc = i / 384;
    u16 v = 0;
    if (oc < 40 && k < 40) v = f2b(w4[oc * 40 + k]);
    wt4[i] = v;
  } else if (i < WT_SET + WCM_SET) {
    int j = i - WT_SET;
    int c = j / 320;
    int rem = j - c * 320;
    int oc = rem >> 3;
    int e = rem & 7;
    int k = c * 8 + e;
    int dy = k >> 7;
    int r = k & 127;
    u16 v = 0;
    if (r < 120) {
      int dx = r / 40;
      int ic = r - dx * 40;
      v = f2b(w3[((oc * 40 + ic) * 3 + dy) * 3 + dx]);
    }
    wcma[j] = v;
  } else {
    int j2 = i - WT_SET - WCM_SET;
    int set3 = j2 / WSC_SET;
    int r3 = j2 - set3 * WSC_SET;
    int c2 = r3 / 320;
    int rem = r3 - c2 * 320;
    int oc = rem >> 3;
    int e = rem & 7;
    u16 v = 0;
    if (c2 < 45) {
      int dy = c2 / 15, cc = c2 % 15;
      int dx = cc / 5, icq = cc % 5;
      int ic = icq * 8 + e;
      const float* w = (set3 == 0) ? w0 : (set3 == 1) ? w2 : w1;
      v = f2b(w[((oc * 40 + ic) * 3 + dy) * 3 + dx]);
    }
    wsc[j2] = v;
  }
}

// ---- zero the halo rings of cl_a -----------------------------------------
__global__ __launch_bounds__(256)
void ringz_k(u16* __restrict__ cla)
{
  const int n = blockIdx.x / IW;
  const int yr = blockIdx.x % IW;
  const int t = threadIdx.x;
  const size_t base = (size_t)n * IMG_CL + (size_t)yr * IWCH;
  const uint4 z = {0u, 0u, 0u, 0u};
  if (yr == 0 || yr == IW - 1) {
    for (int i = t; i < IWCH / 8; i += 256) ((uint4*)(cla + base))[i] = z;
    return;
  }
  if (t < 5) {
    ((uint4*)(cla + base))[t] = z;
  } else if (t < 10) {
    ((uint4*)(cla + base + (size_t)(IW - 1) * CH))[t - 5] = z;
  }
}

// ---- fused conv1+conv5, 512 thr / 8 waves (r17-measured 78us) ------------
__global__ __launch_bounds__(512, 2)
void fconv2p_k(const float* __restrict__ xg, const u16* __restrict__ wscA,
               const u16* __restrict__ wscB, const float* __restrict__ biasA,
               const float* __restrict__ biasB, u16* __restrict__ outA,
               u16* __restrict__ outB)
{
  __shared__ __align__(16) u16 s_mem[30560];   // x 15840 + w 14720 = 61120 B
  u16* s_in = s_mem;
  u16* s_w  = s_mem + 15840;                   // weights; reused as restage

  const int tid = threadIdx.x;
  const int bid = ((int)blockIdx.x & 7) * 256 + ((int)blockIdx.x >> 3);
  const int n = bid >> 8;
  const int tb = bid & 255;
  const int y0 = (tb >> 2) << 2;
  const int x0 = (tb & 3) << 6;

  #pragma unroll
  for (int k = 0; k < 4; ++k) {                // wA: 1840 16B chunks
    int i = tid + (k << 9);
    if (i < 1840) GLDS16(wscA + i * 8, s_w + i * 8);
  }
  // stage x tile (6 rows x 66 px x 40 ic), packed-converting
  const float* xsrc = xg + (size_t)n * CH * 65536;
  if (tid < 396) {
    int slot = tid;
    int r = slot / 66, p = slot - r * 66;
    int gy = y0 + r - 1, gx = x0 + p - 1;
    __attribute__((aligned(16))) u32 buf[20];
    if ((unsigned)gy < 256u && (unsigned)gx < 256u) {
      const float* xp = xsrc + (size_t)gy * 256 + gx;
      #pragma unroll
      for (int icp = 0; icp < 20; ++icp)
        buf[icp] = pkbf(xp[(size_t)(2 * icp) * 65536],
                        xp[(size_t)(2 * icp + 1) * 65536]);
    } else {
      #pragma unroll
      for (int icp = 0; icp < 20; ++icp) buf[icp] = 0u;
    }
    u16* dst = s_in + slot * 40;
    #pragma unroll
    for (int q = 0; q < 5; ++q) ((uint4*)dst)[q] = ((const uint4*)buf)[q];
  }
  __syncthreads();

  const int w = tid >> 6;
  const int ry = w >> 1;                       // output row y0+ry
  const int h = w & 1;                         // x half: px (2h..2h+1)*16
  const int l = tid & 63;
  const int g = l >> 4;
  const int m = l & 15;

  f32x4 accA[2][3], accB[2][3];
  #pragma unroll
  for (int xt = 0; xt < 2; ++xt)
    #pragma unroll
    for (int tt = 0; tt < 3; ++tt) {
      accA[xt][tt] = (f32x4){0.f, 0.f, 0.f, 0.f};
      accB[xt][tt] = (f32x4){0.f, 0.f, 0.f, 0.f};
    }

  // ---- K-loop pass A -----------------------------------------------------
  #pragma unroll
  for (int s = 0; s < 12; ++s) {
    const int dy = s >> 2;
    const int c = ((s & 3) << 2) + g;
    int dx, icb;
    if (c >= 15)      { dx = 0; icb = 0; }
    else if (c >= 10) { dx = 2; icb = (c - 10) * 8; }
    else if (c >= 5)  { dx = 1; icb = (c - 5) * 8; }
    else              { dx = 0; icb = c * 8; }
    const int abase = (ry + dy) * (66 * CH) + ((h * 2) * 16 + m + dx) * CH + icb;
    bf16x8 a0 = *(const bf16x8*)(s_in + abase);
    bf16x8 a1 = *(const bf16x8*)(s_in + abase + 16 * CH);
    const u16* wrow = s_w + ((c >= 15) ? 45 * 320 : (dy * 15 + c) * 320);
    bf16x8 b0 = *(const bf16x8*)(wrow + m * 8);
    bf16x8 b1 = *(const bf16x8*)(wrow + (m + 16) * 8);
    bf16x8 b2 = *(const bf16x8*)(wrow + (m >= 8 ? 312 : (m + 32) * 8));
    accA[0][0] = __builtin_amdgcn_mfma_f32_16x16x32_bf16(b0, a0, accA[0][0], 0, 0, 0);
    accA[1][0] = __builtin_amdgcn_mfma_f32_16x16x32_bf16(b0, a1, accA[1][0], 0, 0, 0);
    accA[0][1] = __builtin_amdgcn_mfma_f32_16x16x32_bf16(b1, a0, accA[0][1], 0, 0, 0);
    accA[1][1] = __builtin_amdgcn_mfma_f32_16x16x32_bf16(b1, a1, accA[1][1], 0, 0, 0);
    accA[0][2] = __builtin_amdgcn_mfma_f32_16x16x32_bf16(b2, a0, accA[0][2], 0, 0, 0);
    accA[1][2] = __builtin_amdgcn_mfma_f32_16x16x32_bf16(b2, a1, accA[1][2], 0, 0, 0);
  }

  __syncthreads();                             // all waves done reading wA
  #pragma unroll
  for (int k = 0; k < 4; ++k) {                // wB into same region
    int i = tid + (k << 9);
    if (i < 1840) GLDS16(wscB + i * 8, s_w + i * 8);
  }
  __syncthreads();                             // wB ready (vmcnt drained)

  // ---- K-loop pass B -----------------------------------------------------
  #pragma unroll
  for (int s = 0; s < 12; ++s) {
    const int dy = s >> 2;
    const int c = ((s & 3) << 2) + g;
    int dx, icb;
    if (c >= 15)      { dx = 0; icb = 0; }
    else if (c >= 10) { dx = 2; icb = (c - 10) * 8; }
    else if (c >= 5)  { dx = 1; icb = (c - 5) * 8; }
    else              { dx = 0; icb = c * 8; }
    const int abase = (ry + dy) * (66 * CH) + ((h * 2) * 16 + m + dx) * CH + icb;
    bf16x8 a0 = *(const bf16x8*)(s_in + abase);
    bf16x8 a1 = *(const bf16x8*)(s_in + abase + 16 * CH);
    const u16* wrow = s_w + ((c >= 15) ? 45 * 320 : (dy * 15 + c) * 320);
    bf16x8 b0 = *(const bf16x8*)(wrow + m * 8);
    bf16x8 b1 = *(const bf16x8*)(wrow + (m + 16) * 8);
    bf16x8 b2 = *(const bf16x8*)(wrow + (m >= 8 ? 312 : (m + 32) * 8));
    accB[0][0] = __builtin_amdgcn_mfma_f32_16x16x32_bf16(b0, a0, accB[0][0], 0, 0, 0);
    accB[1][0] = __builtin_amdgcn_mfma_f32_16x16x32_bf16(b0, a1, accB[1][0], 0, 0, 0);
    accB[0][1] = __builtin_amdgcn_mfma_f32_16x16x32_bf16(b1, a0, accB[0][1], 0, 0, 0);
    accB[1][1] = __builtin_amdgcn_mfma_f32_16x16x32_bf16(b1, a1, accB[1][1], 0, 0, 0);
    accB[0][2] = __builtin_amdgcn_mfma_f32_16x16x32_bf16(b2, a0, accB[0][2], 0, 0, 0);
    accB[1][2] = __builtin_amdgcn_mfma_f32_16x16x32_bf16(b2, a1, accB[1][2], 0, 0, 0);
  }

  __syncthreads();                             // all reads of s_w/s_in done

  float4 bvA[3], bvB[3];
  bvA[0] = *(const float4*)(biasA + 4 * g);
  bvA[1] = *(const float4*)(biasA + 16 + 4 * g);
  bvA[2] = (g < 2) ? *(const float4*)(biasA + 32 + 4 * g) : make_float4(0.f, 0.f, 0.f, 0.f);
  bvB[0] = *(const float4*)(biasB + 4 * g);
  bvB[1] = *(const float4*)(biasB + 16 + 4 * g);
  bvB[2] = (g < 2) ? *(const float4*)(biasB + 32 + 4 * g) : make_float4(0.f, 0.f, 0.f, 0.f);

  // row-shared restage regions: row ry -> s_w + ry*5120 bytes
  char* so = (char*)s_w + ry * 5120;
  const int rdrow = tid >> 7;                  // readback: 128 threads per row
  const int l2 = tid & 127;
  const size_t rowu_rd = (size_t)n * IMG_CL
                       + ((size_t)(y0 + rdrow + 1) * IW + (x0 + 1)) * CH;

  // ---- pass A: restage -> barrier -> readback ----------------------------
  #pragma unroll
  for (int tt = 0; tt < 3; ++tt) {
    if (tt == 2 && g >= 2) continue;
    #pragma unroll
    for (int xt = 0; xt < 2; ++xt) {
      const int pxl = (2 * h + xt) * 16 + m;
      float v[4];
      #pragma unroll
      for (int i = 0; i < 4; ++i)
        v[i] = actf(accA[xt][tt][i] + ((const float*)&bvA[tt])[i], 1);
      uint2 pk;
      pk.x = pkbf(v[0], v[1]);
      pk.y = pkbf(v[2], v[3]);
      int byt = pxl * 80 + (16 * tt + 4 * g) * 2;
      byt ^= ((pxl >> 3) & 7) << 4;
      *(uint2*)(so + byt) = pk;
    }
  }
  __syncthreads();
  {
    const char* ro = (const char*)s_w + rdrow * 5120;
    #pragma unroll
    for (int pass = 0; pass < 3; ++pass) {
      int j = l2 + (pass << 7);
      if (j < 320) {
        int px = j / 5, oct = j % 5;
        int byt = px * 80 + oct * 16;
        byt ^= ((px >> 3) & 7) << 4;
        uint4 d = *(const uint4*)(ro + byt);
        *(uint4*)(outA + rowu_rd + (size_t)px * 40 + oct * 8) = d;
      }
    }
  }
  __syncthreads();

  // ---- pass B ------------------------------------------------------------
  #pragma unroll
  for (int tt = 0; tt < 3; ++tt) {
    if (tt == 2 && g >= 2) continue;
    #pragma unroll
    for (int xt = 0; xt < 2; ++xt) {
      const int pxl = (2 * h + xt) * 16 + m;
      float v[4];
      #pragma unroll
      for (int i = 0; i < 4; ++i)
        v[i] = actf(accB[xt][tt][i] + ((const float*)&bvB[tt])[i], 2);
      uint2 pk;
      pk.x = pkbf(v[0], v[1]);
      pk.y = pkbf(v[2], v[3]);
      int byt = pxl * 80 + (16 * tt + 4 * g) * 2;
      byt ^= ((pxl >> 3) & 7) << 4;
      *(uint2*)(so + byt) = pk;
    }
  }
  __syncthreads();
  {
    const char* ro = (const char*)s_w + rdrow * 5120;
    #pragma unroll
    for (int pass = 0; pass < 3; ++pass) {
      int j = l2 + (pass << 7);
      if (j < 320) {
        int px = j / 5, oct = j % 5;
        int byt = px * 80 + oct * 16;
        byt ^= ((px >> 3) & 7) << 4;
        uint4 d = *(const uint4*)(ro + byt);
        *(uint4*)(outB + rowu_rd + (size_t)px * 40 + oct * 8) = d;
      }
    }
  }
}

// ---- conv7: all-LDS MFMA conv 3x3, planar f32 out (r17-measured) ---------
__global__ __launch_bounds__(512, 2)
void convl_k(const u16* __restrict__ incl, const u16* __restrict__ wcm,
             const float* __restrict__ bias, float* __restrict__ outp)
{
  __shared__ __align__(16) u16 s_mem[31200];   // input 15840 + weights 15360
  u16* s_in = s_mem;
  u16* s_w  = s_mem + 15840;

  const int tid = threadIdx.x;
  const int bid = ((int)blockIdx.x & 7) * 256 + ((int)blockIdx.x >> 3);
  const int n = bid >> 8;
  const int tb = bid & 255;
  const int y0 = (tb >> 2) << 2;
  const int x0 = (tb & 3) << 6;

  const u16* src = incl + (size_t)n * IMG_CL + ((size_t)y0 * IW + x0) * CH;
  #pragma unroll
  for (int k = 0; k < 4; ++k) {
    int i = tid + (k << 9);
    if (i < 1980) {
      int r = i / 330, o = i - r * 330;
      GLDS16(src + (size_t)r * IWCH + o * 8, s_in + i * 8);
    }
  }
  #pragma unroll
  for (int k = 0; k < 4; ++k) {
    int i = tid + (k << 9);
    if (i < 1920) GLDS16(wcm + i * 8, s_w + i * 8);
  }
  __syncthreads();

  const int w = tid >> 6;
  const int ry = w >> 1;
  const int h = w & 1;
  const int l = tid & 63;
  const int g = l >> 4;
  const int m = l & 15;

  f32x4 acc[2][3];
  #pragma unroll
  for (int xt = 0; xt < 2; ++xt)
    #pragma unroll
    for (int tt = 0; tt < 3; ++tt) acc[xt][tt] = (f32x4){0.f, 0.f, 0.f, 0.f};

  #pragma unroll
  for (int s = 0; s < 12; ++s) {
    const int dy = s >> 2;
    const int c = ((s & 3) << 2) + g;
    int dx, icb;
    if (c >= 15)      { dx = 0; icb = 0; }
    else if (c >= 10) { dx = 2; icb = (c - 10) * 8; }
    else if (c >= 5)  { dx = 1; icb = (c - 5) * 8; }
    else              { dx = 0; icb = c * 8; }
    const int abase = (ry + dy) * (66 * CH) + ((h * 2) * 16 + m + dx) * CH + icb;
    bf16x8 a0 = *(const bf16x8*)(s_in + abase);
    bf16x8 a1 = *(const bf16x8*)(s_in + abase + 16 * CH);

    const int ch = (s << 2) + g;
    const u16* wrow = s_w + ch * 320;
    bf16x8 b0 = *(const bf16x8*)(wrow + m * 8);
    bf16x8 b1 = *(const bf16x8*)(wrow + (m + 16) * 8);
    bf16x8 b2 = *(const bf16x8*)(wrow + (m >= 8 ? 312 : (m + 32) * 8));

    acc[0][0] = __builtin_amdgcn_mfma_f32_16x16x32_bf16(a0, b0, acc[0][0], 0, 0, 0);
    acc[1][0] = __builtin_amdgcn_mfma_f32_16x16x32_bf16(a1, b0, acc[1][0], 0, 0, 0);
    acc[0][1] = __builtin_amdgcn_mfma_f32_16x16x32_bf16(a0, b1, acc[0][1], 0, 0, 0);
    acc[1][1] = __builtin_amdgcn_mfma_f32_16x16x32_bf16(a1, b1, acc[1][1], 0, 0, 0);
    acc[0][2] = __builtin_amdgcn_mfma_f32_16x16x32_bf16(a0, b2, acc[0][2], 0, 0, 0);
    acc[1][2] = __builtin_amdgcn_mfma_f32_16x16x32_bf16(a1, b2, acc[1][2], 0, 0, 0);
  }

  const int y = y0 + ry;
  const float bv0 = bias[m];
  const float bv1 = bias[m + 16];
  const float bv2 = (m < 8) ? bias[m + 32] : 0.f;
  #pragma unroll
  for (int tt = 0; tt < 3; ++tt) {
    const int oc = m + 16 * tt;
    if (tt == 2 && m >= 8) continue;
    const float bv = (tt == 0) ? bv0 : (tt == 1) ? bv1 : bv2;
    #pragma unroll
    for (int xt = 0; xt < 2; ++xt) {
      const int xb = x0 + (2 * h + xt) * 16 + 4 * g;
      float v[4];
      #pragma unroll
      for (int i = 0; i < 4; ++i) v[i] = acc[xt][tt][i] + bv;
      *(float4*)(outp + (((size_t)(n * CH + oc)) << 16) + ((size_t)y << 8) + xb)
          = make_float4(v[0], v[1], v[2], v[3]);
    }
  }
}

// ---- SPARSE conv2 (r13-verified) -----------------------------------------
__global__ __launch_bounds__(256, 2)
void sconv_k(const u16* __restrict__ cla, const u16* __restrict__ wsc,
             const float* __restrict__ bias, u16* __restrict__ ddc)
{
  __shared__ __align__(16) u16 s_mem[32640];   // s_in 17920 + s_w 14720
  u16* s_in = s_mem;
  u16* s_w  = s_mem + 17920;

  const int tid = threadIdx.x;
  const int bid = ((int)blockIdx.x & 7) * 128 + ((int)blockIdx.x >> 3); // 1024
  const int n = bid >> 7;
  const int oy = (bid >> 2) & 31;
  const int xg = bid & 3;

  const u16* src = cla + (ptrdiff_t)((size_t)n * IMG_CL)
                       + (ptrdiff_t)(8 * oy - 2) * IWCH + (64 * xg - 2) * CH;
  #pragma unroll
  for (int k = 0; k < 9; ++k) {
    int i = tid + (k << 8);
    if (i < 2240) {
      int r = i / 320, o = i - r * 320;
      GLDS16(src + (ptrdiff_t)r * IWCH + o * 8, s_in + i * 8);
    }
  }
  #pragma unroll
  for (int k = 0; k < 8; ++k) {
    int i = tid + (k << 8);
    if (i < 1840) GLDS16(wsc + i * 8, s_w + i * 8);
  }
  __syncthreads();

  const int w = tid >> 6;
  const int l = tid & 63;
  const int g = l >> 4;
  const int m = l & 15;

  const int p0 = m;
  const int p1 = (m < 8) ? 16 + m : 23;
  const int rb0 = 8 * (p0 / 3) + 2 * (p0 % 3);
  const int rb1 = 8 * (p1 / 3) + 2 * (p1 % 3);

  f32x4 acc[2][3];
  #pragma unroll
  for (int mt = 0; mt < 2; ++mt)
    #pragma unroll
    for (int tt = 0; tt < 3; ++tt) acc[mt][tt] = (f32x4){0.f, 0.f, 0.f, 0.f};

  if (w < 3) {
    #pragma unroll
    for (int s = 0; s < 12; ++s) {
      const int dy = s >> 2;
      const int c = ((s & 3) << 2) + g;
      int dx, icb;
      if (c >= 15)      { dx = 0; icb = 0; }
      else if (c >= 10) { dx = 2; icb = (c - 10) * 8; }
      else if (c >= 5)  { dx = 1; icb = (c - 5) * 8; }
      else              { dx = 0; icb = c * 8; }
      const int rowb = (2 * w + dy) * 2560;
      bf16x8 a0 = *(const bf16x8*)(s_in + rowb + (rb0 + dx) * CH + icb);
      bf16x8 a1 = *(const bf16x8*)(s_in + rowb + (rb1 + dx) * CH + icb);

      const u16* wrow = s_w + ((c == 15) ? 45 * 320 : (dy * 15 + c) * 320);
      bf16x8 b0 = *(const bf16x8*)(wrow + m * 8);
      bf16x8 b1 = *(const bf16x8*)(wrow + (m + 16) * 8);
      bf16x8 b2 = *(const bf16x8*)(wrow + (m >= 8 ? 312 : (m + 32) * 8));

      acc[0][0] = __builtin_amdgcn_mfma_f32_16x16x32_bf16(b0, a0, acc[0][0], 0, 0, 0);
      acc[1][0] = __builtin_amdgcn_mfma_f32_16x16x32_bf16(b0, a1, acc[1][0], 0, 0, 0);
      acc[0][1] = __builtin_amdgcn_mfma_f32_16x16x32_bf16(b1, a0, acc[0][1], 0, 0, 0);
      acc[1][1] = __builtin_amdgcn_mfma_f32_16x16x32_bf16(b1, a1, acc[1][1], 0, 0, 0);
      acc[0][2] = __builtin_amdgcn_mfma_f32_16x16x32_bf16(b2, a0, acc[0][2], 0, 0, 0);
      acc[1][2] = __builtin_amdgcn_mfma_f32_16x16x32_bf16(b2, a1, acc[1][2], 0, 0, 0);
    }
  }

  __syncthreads();
  if (w == 3) return;

  char* so = (char*)s_w + w * 2048;
  float4 bv[3];
  bv[0] = *(const float4*)(bias + 4 * g);
  bv[1] = *(const float4*)(bias + 16 + 4 * g);
  bv[2] = (g < 2) ? *(const float4*)(bias + 32 + 4 * g)
                  : make_float4(0.f, 0.f, 0.f, 0.f);
  #pragma unroll
  for (int tt = 0; tt < 3; ++tt) {
    if (tt == 2 && g >= 2) continue;
    #pragma unroll
    for (int mt = 0; mt < 2; ++mt) {
      const int p = mt * 16 + m;
      if (p >= 24) continue;
      float v[4];
      #pragma unroll
      for (int i = 0; i < 4; ++i)
        v[i] = actf(acc[mt][tt][i] + ((const float*)&bv[tt])[i], 1);
      uint2 pk;
      pk.x = pkbf(v[0], v[1]);
      pk.y = pkbf(v[2], v[3]);
      int byt = p * 80 + (16 * tt + 4 * g) * 2;
      byt ^= ((p >> 3) & 7) << 4;
      *(uint2*)(so + byt) = pk;
    }
  }

  const int yi = oy * 3 + w;
  const int y = 8 * oy - 2 + 2 * w;
  const bool rowinv = (y < 0);
  #pragma unroll
  for (int pass = 0; pass < 2; ++pass) {
    int j = pass * 64 + l;
    if (j >= 120) continue;
    int p = j / 5, oct = j % 5;
    int byt = p * 80 + oct * 16;
    byt ^= ((p >> 3) & 7) << 4;
    uint4 d = *(const uint4*)(so + byt);
    int x = 64 * xg + 8 * (p / 3) + 2 * (p % 3) - 2;
    if (rowinv || x < 0) {
      d = (uint4){0u, 0u, 0u, 0u};
    } else {
      const u16* rp = cla + (size_t)n * IMG_CL
                    + ((size_t)(y + 1) * IW + (x + 1)) * CH + oct * 8;
      uint4 rv = *(const uint4*)rp;
      d.x = addbf2(d.x, rv.x); d.y = addbf2(d.y, rv.y);
      d.z = addbf2(d.z, rv.z); d.w = addbf2(d.w, rv.w);
    }
    *(uint4*)(ddc + (((size_t)(n * 96 + yi)) * 96 + 24 * xg + p) * CH + oct * 8) = d;
  }
}

// ---- depthwise conv on compact dd (r17: c fastest -> coalesced taps) -----
__global__ __launch_bounds__(256)
void dwconv_c(const u16* __restrict__ ddc, const float* __restrict__ w,
              const float* __restrict__ b, float* __restrict__ out)
{
  int idx = blockIdx.x * 256 + threadIdx.x;
  if (idx >= 8 * 32 * 32 * CH) return;
  int c = idx % CH;
  int p = idx / CH;
  int ox = p & 31;
  int oy = (p >> 5) & 31;
  int n = p >> 10;
  float acc = b[c];
  const u16* base = ddc + (((size_t)(n * 96 + oy * 3)) * 96 + ox * 3) * CH + c;
  #pragma unroll
  for (int dyi = 0; dyi < 3; ++dyi)
    #pragma unroll
    for (int dxi = 0; dxi < 3; ++dxi)
      acc += w[c * 9 + dyi * 3 + dxi] * b2f(base[((size_t)dyi * 96 + dxi) * CH]);
  out[((size_t)(n * CH + c) << 10) + oy * 32 + ox] = acc;
}

// ---- per-8x8-block iDCT on planar f32 32x32 ------------------------------
__global__ __launch_bounds__(256)
void idct8_k(const float* __restrict__ in, float* __restrict__ out)
{
  __shared__ float ctab[8];
  if (threadIdx.x < 8) {
    const float c_[8] = {1.f, 0.70710678118654752f, 0.f, -0.70710678118654752f,
                         -1.f, -0.70710678118654752f, 0.f, 0.70710678118654752f};
    ctab[threadIdx.x] = c_[threadIdx.x];
  }
  __syncthreads();
  int idx = blockIdx.x * 256 + threadIdx.x;
  if (idx >= 8 * CH * 32 * 32) return;
  int ox = idx & 31, oy = (idx >> 5) & 31, bc = idx >> 10;
  int k = oy & 7, lq = ox & 7;
  const float* ip = in + bc * 1024 + (oy & ~7) * 32 + (ox & ~7);
  float acc = 0.f;
  #pragma unroll
  for (int mm = 0; mm < 8; ++mm) {
    float rk = ctab[(k * mm) & 7];
    float s = 0.f;
    #pragma unroll
    for (int nn = 0; nn < 8; ++nn)
      s += ctab[(lq * nn) & 7] * ip[mm * 32 + nn];
    acc += rk * s;
  }
  out[idx] = acc * 0.125f;
}

// ---- MFMA 1x1 conv + sigmoid + bilinear(32->256) multiply; cl bf16 -------
__global__ __launch_bounds__(256)
void wgtmul_k(const u16* __restrict__ t1cl, const u16* __restrict__ wt3,
              const float* __restrict__ b3, const float* __restrict__ dct,
              u16* __restrict__ outcl)
{
  __shared__ float s_yw[40 * 33];
  __shared__ u16 s_out[4 * 3072];

  const int q8 = (int)gridDim.x >> 3;
  const int bid = ((int)blockIdx.x & 7) * q8 + ((int)blockIdx.x >> 3);
  const int n = bid >> 8;
  const int y = bid & 255;
  const int tid = threadIdx.x;

  float sy = (y + 0.5f) * 0.125f - 0.5f;
  float yq = floorf(sy);
  float fy = sy - yq;
  int y0c = max((int)yq, 0), y1c = min((int)yq + 1, 31);

  for (int i = tid; i < 1280; i += 256) {
    int oc = i >> 5, c = i & 31;
    const float* sp = dct + ((size_t)(n * CH + oc) << 10);
    s_yw[oc * 33 + c] = (1.f - fy) * sp[y0c * 32 + c] + fy * sp[y1c * 32 + c];
  }
  __syncthreads();

  const int w = tid >> 6;
  const int l = tid & 63;
  const int g = l >> 4;
  const int m = l & 15;
  const int xb = w << 6;

  const u16* tp = t1cl + (size_t)n * IMG_CL + ((size_t)(y + 1) * IW + 1) * CH;

  f32x4 acc[4][3];
  #pragma unroll
  for (int xt = 0; xt < 4; ++xt)
    #pragma unroll
    for (int t = 0; t < 3; ++t) acc[xt][t] = (f32x4){0.f, 0.f, 0.f, 0.f};

  #pragma unroll
  for (int xt = 0; xt < 4; ++xt) {
    const u16* ap = tp + (size_t)(xb + xt * 16 + m) * CH;
    bf16x8 a0 = *(const bf16x8*)(ap + 8 * g);
    bf16x8 a1 = *(const bf16x8*)(ap + 32 + 8 * g);
    #pragma unroll
    for (int t = 0; t < 3; ++t) {
      bf16x8 b0 = *(const bf16x8*)(wt3 + (m + 16 * t) * 384 + 8 * g);
      bf16x8 b1 = *(const bf16x8*)(wt3 + (m + 16 * t) * 384 + 32 + 8 * g);
      acc[xt][t] = __builtin_amdgcn_mfma_f32_16x16x32_bf16(b0, a0, acc[xt][t], 0, 0, 0);
      acc[xt][t] = __builtin_amdgcn_mfma_f32_16x16x32_bf16(b1, a1, acc[xt][t], 0, 0, 0);
    }
  }

  u16* so = s_out + w * 3072;
  float4 bv[3];
  bv[0] = *(const float4*)(b3 + 4 * g);
  bv[1] = *(const float4*)(b3 + 16 + 4 * g);
  bv[2] = (g < 2) ? *(const float4*)(b3 + 32 + 4 * g) : make_float4(0.f, 0.f, 0.f, 0.f);
  #pragma unroll
  for (int t = 0; t < 3; ++t) {
    if (t == 2 && g >= 2) continue;
    #pragma unroll
    for (int xt = 0; xt < 4; ++xt) {
      const int pxl = xt * 16 + m;
      const int px = xb + pxl;
      float sx = (px + 0.5f) * 0.125f - 0.5f;
      float xq = floorf(sx);
      float fx = sx - xq;
      int x0c = max((int)xq, 0), x1c = min((int)xq + 1, 31);
      float r4[4];
      #pragma unroll
      for (int i = 0; i < 4; ++i) {
        int oc = 16 * t + 4 * g + i;
        float wgt = 1.f / (1.f + __expf(-(acc[xt][t][i] + ((const float*)&bv[t])[i])));
        float bil = (1.f - fx) * s_yw[oc * 33 + x0c] + fx * s_yw[oc * 33 + x1c];
        r4[i] = wgt * bil;
      }
      uint2 pk;
      pk.x = pkbf(r4[0], r4[1]);
      pk.y = pkbf(r4[2], r4[3]);
      int byt = pxl * 80 + (16 * t + 4 * g) * 2;
      byt ^= ((pxl >> 3) & 7) << 4;
      *(uint2*)((char*)so + byt) = pk;
    }
  }
  const size_t rowu = (size_t)n * IMG_CL + ((size_t)(y + 1) * IW + (xb + 1)) * CH;
  #pragma unroll
  for (int q = 0; q < 5; ++q) {
    int byt = l * 80 + q * 16;
    byt ^= ((l >> 3) & 7) << 4;
    uint4 d = *(const uint4*)((const char*)so + byt);
    *(uint4*)(outcl + rowu + (size_t)l * 40 + q * 8) = d;
  }
}

extern "C" void kernel_launch(void* const* d_in, const int* in_sizes, int n_in,
                              void* d_out, int out_size, void* d_ws, size_t ws_size,
                              hipStream_t stream)
{
  const float* x       = (const float*)d_in[0];
  const float* conv_w  = (const float*)d_in[1];
  const float* conv_b  = (const float*)d_in[2];
  const float* ddct_w  = (const float*)d_in[3];
  const float* ddct_b  = (const float*)d_in[4];
  const float* dctc_w  = (const float*)d_in[5];
  const float* dctc_b  = (const float*)d_in[6];
  const float* w1_w    = (const float*)d_in[7];
  const float* w1_b    = (const float*)d_in[8];
  const float* w3_w    = (const float*)d_in[9];
  const float* w3_b    = (const float*)d_in[10];
  const float* after_w = (const float*)d_in[11];
  const float* after_b = (const float*)d_in[12];

  char* ws = (char*)d_ws;
  const size_t CLB = (size_t)8 * IMG_CL * 2;          // 42,600,960 B
  float* small0 = (float*)ws;                         // 1,310,720
  float* small1 = (float*)(ws + 1310720);             // 1,310,720
  u16*   wt4    = (u16*)(ws + 2621440);               // 36,864 (w3 rm)
  u16*   wcma   = (u16*)(ws + 2658304);               // 30,720 (after cm)
  u16*   wsc    = (u16*)(ws + 2689024);               // 88,320 (3 compressed)
  u16*   ddc    = (u16*)(ws + 2777344);               // 5,898,240 compact dd
  u16*   cl_a   = (u16*)(ws + 8675584);               // dct_feat, later prod
  u16*   cl_c   = (u16*)(ws + 8675584 + CLB);         // t1

  // 0. weight transforms + cl_a ring zeroing
  prep_w_k<<<305, 256, 0, stream>>>(conv_w, ddct_w, w1_w, after_w, w3_w,
                                    wt4, wcma, wsc);
  ringz_k<<<8 * IW, 256, 0, stream>>>(cl_a);
  // 1+5. dct_feat = gelu(conv1(x)) -> cl_a ; t1 = relu(conv5(x)) -> cl_c
  fconv2p_k<<<2048, 512, 0, stream>>>(x, wsc, wsc + WSC_SET,
                                      conv_b, w1_b, cl_a, cl_c);
  // 2. SPARSE dd at dwconv sample points           -> ddc (compact)
  sconv_k<<<1024, 256, 0, stream>>>(cl_a, wsc + 2 * WSC_SET, ddct_b, ddc);
  // 3. depthwise strided conv on compact dd        -> small0
  dwconv_c<<<1280, 256, 0, stream>>>(ddc, dctc_w, dctc_b, small0);
  // 4. per-block 8x8 iDCT                          -> small1
  idct8_k<<<1280, 256, 0, stream>>>(small0, small1);
  // 6. prod = sigmoid(1x1(t1)) * bilinear(idct)    -> cl_a (dct_feat dead)
  wgtmul_k<<<2048, 256, 0, stream>>>(cl_c, wt4, w3_b, small1, cl_a);
  // 7. out = conv(prod, after)                     -> d_out fp32 planar
  convl_k<<<2048, 512, 0, stream>>>(cl_a, wcma, after_b, (float*)d_out);
}